// Round 6
// baseline (360.683 us; speedup 1.0000x reference)
//
#include <hip/hip_runtime.h>
#include <hip/hip_bf16.h>
#include <stdint.h>

#define DIM 768
#define SEQ 2048
#define TOKENS 4096
#define HEADS 12
#define DFF 3072
#define COND 128
#define ADA6 4608

typedef __attribute__((ext_vector_type(8))) short bf16x8;
typedef __attribute__((ext_vector_type(4))) float f32x4;

#define MFMA16x32(a, b, c) __builtin_amdgcn_mfma_f32_16x16x32_bf16(a, b, c, 0, 0, 0)
#define GLDS16(g, l)                                                                  \
    __builtin_amdgcn_global_load_lds((const __attribute__((address_space(1))) void*)(g), \
                                     (__attribute__((address_space(3))) void*)(l), 16, 0, 0)

__device__ __forceinline__ ushort f2bf(float f) {
    union { float f; uint32_t u; } v;
    v.f = f;
    uint32_t r = v.u + 0x7FFF + ((v.u >> 16) & 1);
    return (ushort)(r >> 16);
}

__device__ __forceinline__ uint32_t packbf2(float a, float b) {
    union { __hip_bfloat162 h; uint32_t u; } cv;
    cv.h = __float22bfloat162_rn(make_float2(a, b));
    return cv.u;
}

// ---------------- ada = c @ ada_w + ada_b  (2 x 4608, fp32) ----------------
__global__ void ada_kernel(const float* __restrict__ c, const float* __restrict__ ada_w,
                           const float* __restrict__ ada_b, float* __restrict__ ada) {
    int j = blockIdx.x * 256 + threadIdx.x;
    int bb = blockIdx.y;
    if (j < ADA6) {
        float acc = ada_b[j];
        for (int k = 0; k < COND; ++k)
            acc = fmaf(c[bb * COND + k], ada_w[(long)k * ADA6 + j], acc);
        ada[bb * ADA6 + j] = acc;
    }
}

// ------------- weight convert + transpose: W[K][N] f32 -> Wt[N][K] bf16 -------------
__global__ __launch_bounds__(256) void convT(const float* __restrict__ W,
                                             ushort* __restrict__ Wt, int K, int N) {
    __shared__ float t[64][65];
    int tid = threadIdx.x;
    int n0 = blockIdx.x * 64, k0 = blockIdx.y * 64;
#pragma unroll
    for (int it = 0; it < 4; ++it) {
        int idx = it * 256 + tid;
        int kr = idx >> 4, nc = (idx & 15) * 4;
        float4 v = *(const float4*)&W[(long)(k0 + kr) * N + n0 + nc];
        t[kr][nc] = v.x; t[kr][nc + 1] = v.y; t[kr][nc + 2] = v.z; t[kr][nc + 3] = v.w;
    }
    __syncthreads();
#pragma unroll
    for (int it = 0; it < 4; ++it) {
        int idx = it * 256 + tid;
        int nr = idx >> 4, kc = (idx & 15) * 4;
        ushort4 v;
        v.x = f2bf(t[kc][nr]); v.y = f2bf(t[kc + 1][nr]);
        v.z = f2bf(t[kc + 2][nr]); v.w = f2bf(t[kc + 3][nr]);
        *(ushort4*)&Wt[(long)(n0 + nr) * K + k0 + kc] = v;
    }
}

// ---------------- layernorm + adaLN modulate -> bf16 ----------------
__global__ __launch_bounds__(256) void ln_mod_kernel(const float* __restrict__ x,
                                                     const float* __restrict__ w,
                                                     const float* __restrict__ ada,
                                                     int shiftOff, int scaleOff,
                                                     ushort* __restrict__ out) {
    int token = blockIdx.x;
    int bb = token >> 11;
    int tid = threadIdx.x;
    const float* xi = x + (long)token * DIM;
    float v[3];
    float sum = 0.f, sumsq = 0.f;
#pragma unroll
    for (int t = 0; t < 3; ++t) {
        float val = xi[tid + 256 * t];
        v[t] = val;
        sum += val;
        sumsq = fmaf(val, val, sumsq);
    }
    for (int msk = 1; msk < 64; msk <<= 1) {
        sum += __shfl_xor(sum, msk, 64);
        sumsq += __shfl_xor(sumsq, msk, 64);
    }
    __shared__ float red0[4], red1[4];
    int wave = tid >> 6;
    if ((tid & 63) == 0) { red0[wave] = sum; red1[wave] = sumsq; }
    __syncthreads();
    sum = red0[0] + red0[1] + red0[2] + red0[3];
    sumsq = red1[0] + red1[1] + red1[2] + red1[3];
    float mu = sum * (1.f / DIM);
    float var = sumsq * (1.f / DIM) - mu * mu;
    float rs = rsqrtf(var + 1e-5f);
    const float* sh = ada + bb * ADA6 + shiftOff;
    const float* sc = ada + bb * ADA6 + scaleOff;
    ushort* oi = out + (long)token * DIM;
#pragma unroll
    for (int t = 0; t < 3; ++t) {
        int j = tid + 256 * t;
        oi[j] = f2bf((v[t] - mu) * rs * w[j] * (1.f + sc[j]) + sh[j]);
    }
}

// ---------------- bf16 MFMA GEMM, BMx128 tile, BK=64, 4 waves, XCD swizzle ----------------
// A[M][K] bf16 row-major, B = Wt[N][K] bf16 row-major.  C = A @ Wt^T.
// EPI 0: rope -> bf16 (qkv); 1: gate*acc+skip -> f32; 2: gelu(acc+bias) -> bf16;
// EPI 3: gate*(acc+bias)+skip -> f32
template <int EPI, int BM>
__global__ __launch_bounds__(256) void gemm_bf16(const ushort* __restrict__ A,
                                                 const ushort* __restrict__ B,
                                                 void* __restrict__ Cp, int M, int N, int K,
                                                 const float* __restrict__ bias,
                                                 const float* __restrict__ gate,
                                                 const float* __restrict__ skip,
                                                 const float* __restrict__ cosT,
                                                 const float* __restrict__ sinT) {
    constexpr int MR = BM / 32;  // frags per wave in M
    __shared__ ushort As[BM * 64];
    __shared__ ushort Bs[128 * 64];
    const int tid = threadIdx.x;
    const int wave = tid >> 6, lane = tid & 63;
    const int lo = lane & 15, hi = lane >> 4;
    const int wr = wave >> 1, wc = wave & 1;
    // bijective XCD swizzle (all grids are multiples of 8 blocks)
    const int gx = gridDim.x;
    const int nwg = gx * gridDim.y;
    const int flat = blockIdx.y * gx + blockIdx.x;
    const int swzid = (flat & 7) * (nwg >> 3) + (flat >> 3);
    const int row0 = (swzid / gx) * BM, col0 = (swzid % gx) * 128;
    const int srow = tid >> 3;       // 0..31
    const int scol = (tid & 7) * 8;  // k elems
    f32x4 acc[MR][4] = {};
    const long astep = (long)32 * K;
    const ushort* Ag = A + (long)(row0 + srow) * K + scol;
    const ushort* Bg = B + (long)(col0 + srow) * K + scol;
    for (int k0 = 0; k0 < K; k0 += 64) {
        __syncthreads();
#pragma unroll
        for (int t = 0; t < MR; ++t)
            GLDS16(Ag + t * astep + k0, (char*)As + (t * 256 + tid) * 16);
#pragma unroll
        for (int t = 0; t < 4; ++t)
            GLDS16(Bg + t * astep + k0, (char*)Bs + (t * 256 + tid) * 16);
        __syncthreads();
#pragma unroll
        for (int kk = 0; kk < 2; ++kk) {
            bf16x8 af[MR], bfr[4];
#pragma unroll
            for (int m = 0; m < MR; ++m)
                af[m] = *(const bf16x8*)&As[(wr * (BM / 2) + m * 16 + lo) * 64 + kk * 32 + hi * 8];
#pragma unroll
            for (int n = 0; n < 4; ++n)
                bfr[n] = *(const bf16x8*)&Bs[(wc * 64 + n * 16 + lo) * 64 + kk * 32 + hi * 8];
#pragma unroll
            for (int m = 0; m < MR; ++m)
#pragma unroll
                for (int n = 0; n < 4; ++n)
                    acc[m][n] = MFMA16x32(af[m], bfr[n], acc[m][n]);
        }
    }
    // epilogue: lane holds C[row0+wr*(BM/2)+m*16+hi*4+reg][col0+wc*64+n*16+lo]
    if (EPI == 0) {
        ushort* C = (ushort*)Cp;
#pragma unroll
        for (int m = 0; m < MR; ++m)
#pragma unroll
            for (int reg = 0; reg < 4; ++reg) {
                int r = row0 + wr * (BM / 2) + m * 16 + hi * 4 + reg;
                int pos = r & 1023;
                const float* cb = cosT + pos * 64;
                const float* sb = sinT + pos * 64;
                long rb = (long)r * N + col0 + wc * 64;
#pragma unroll
                for (int pr = 0; pr < 2; ++pr) {
                    int i = pr * 16 + lo;
                    float v0 = acc[m][pr][reg], v1 = acc[m][pr + 2][reg];
                    float c0 = cb[i], s0 = sb[i], c1 = cb[i + 32], s1 = sb[i + 32];
                    C[rb + i] = f2bf(v0 * c0 - v1 * s0);
                    C[rb + i + 32] = f2bf(v1 * c1 + v0 * s1);
                }
            }
    } else if (EPI == 1) {
        float* C = (float*)Cp;
#pragma unroll
        for (int m = 0; m < MR; ++m)
#pragma unroll
            for (int reg = 0; reg < 4; ++reg) {
                int r = row0 + wr * (BM / 2) + m * 16 + hi * 4 + reg;
                int bbi = r >> 11;
#pragma unroll
                for (int n = 0; n < 4; ++n) {
                    int c = col0 + wc * 64 + n * 16 + lo;
                    C[(long)r * N + c] =
                        gate[bbi * ADA6 + c] * acc[m][n][reg] + skip[(long)r * DIM + c];
                }
            }
    } else if (EPI == 2) {
        ushort* C = (ushort*)Cp;
#pragma unroll
        for (int m = 0; m < MR; ++m)
#pragma unroll
            for (int reg = 0; reg < 4; ++reg) {
                int r = row0 + wr * (BM / 2) + m * 16 + hi * 4 + reg;
#pragma unroll
                for (int n = 0; n < 4; ++n) {
                    int c = col0 + wc * 64 + n * 16 + lo;
                    float v = acc[m][n][reg] + bias[c];
                    float g = v / (1.f + __expf(-1.5957691216f * (v + 0.044715f * v * v * v)));
                    C[(long)r * N + c] = f2bf(g);
                }
            }
    } else {
        float* C = (float*)Cp;
#pragma unroll
        for (int m = 0; m < MR; ++m)
#pragma unroll
            for (int reg = 0; reg < 4; ++reg) {
                int r = row0 + wr * (BM / 2) + m * 16 + hi * 4 + reg;
                int bbi = r >> 11;
#pragma unroll
                for (int n = 0; n < 4; ++n) {
                    int c = col0 + wc * 64 + n * 16 + lo;
                    C[(long)r * N + c] = gate[bbi * ADA6 + c] * (acc[m][n][reg] + bias[c]) +
                                         skip[(long)r * DIM + c];
                }
            }
    }
}

// ------------- V transpose: qkv[tok][1536+h*64+d] -> vt[(bb*12+h)*64+d][tok] -------------
__global__ __launch_bounds__(256) void vtrans(const ushort* __restrict__ qkv,
                                              ushort* __restrict__ vt) {
    __shared__ ushort t[64][65];
    int tid = threadIdx.x;
    int tb = blockIdx.x;
    int head = blockIdx.y;
    int bb = blockIdx.z;
#pragma unroll
    for (int it = 0; it < 4; ++it) {
        int idx = it * 256 + tid;
        int tok = idx >> 4, d4 = (idx & 15) * 4;
        const ushort* p = qkv + ((long)bb * SEQ + tb * 64 + tok) * 2304 + 1536 + head * 64 + d4;
        ushort4 v = *(const ushort4*)p;
        t[tok][d4] = v.x; t[tok][d4 + 1] = v.y; t[tok][d4 + 2] = v.z; t[tok][d4 + 3] = v.w;
    }
    __syncthreads();
#pragma unroll
    for (int it = 0; it < 4; ++it) {
        int idx = it * 256 + tid;
        int d = idx >> 4, t4 = (idx & 15) * 4;
        ushort4 v;
        v.x = t[t4][d]; v.y = t[t4 + 1][d]; v.z = t[t4 + 2][d]; v.w = t[t4 + 3][d];
        *(ushort4*)&vt[((long)(bb * HEADS + head) * 64 + d) * SEQ + tb * 64 + t4] = v;
    }
}

// ---------------- MFMA flash attention: split-KV + register pipeline ----------------
// grid (128 qb, 12 heads, 2 bb), 256 thr. 4 waves share (qb, head), strided chunks.
// Straight-line loads (no guards; all over-reads in-bounds, masked P == 0 exactly).
// Pipeline: V(i) and K(i+1) issued before QK(i) compute.
__global__ __launch_bounds__(256) void attn_mfma(const ushort* __restrict__ qkv,
                                                 const ushort* __restrict__ vt,
                                                 ushort* __restrict__ o) {
    __shared__ char ps[4 * 2048];
    __shared__ float lds_m[4][16], lds_l[4][16];
    __shared__ float lds_o[4][64][16];
    const int tid = threadIdx.x;
    const int wave = tid >> 6, lane = tid & 63;
    const int lo = lane & 15, hi = lane >> 4;
    const int bx = blockIdx.x;
    const int qb = (bx & 1) ? (63 - (bx >> 1)) : (127 - (bx >> 1));  // heavy first
    const int head = blockIdx.y;
    const int bb = blockIdx.z;
    char* psb = ps + wave * 2048;
    const int swz = (lo & 7) << 4;
    const long row0 = (long)bb * SEQ + qb * 16;
    const ushort* Qp = qkv + (row0 + lo) * 2304 + head * 64 + hi * 8;
    bf16x8 qf0 = *(const bf16x8*)Qp;
    bf16x8 qf1 = *(const bf16x8*)(Qp + 32);
    f32x4 oacc[4] = {};
    float m_run = -3.0e38f, l_run = 0.f;
    // K row (base + n*16 + lo):  Kb + (base + n*16) * 2304
    const ushort* Kb = qkv + ((long)bb * SEQ + lo) * 2304 + DIM + head * 64 + hi * 8;
    // V row (dt*16 + lo), col base:  Vbs + dt*16*SEQ + base
    const ushort* Vbs = vt + ((long)(bb * HEADS + head) * 64 + lo) * SEQ + hi * 8;

    const int R = (qb < 64) ? qb * 16 : (qb - 63) * 16;  // second-half run length
    const int Rc = (R + 63) >> 6;
    const int nrun = (Rc > wave) ? ((Rc - wave + 3) >> 2) : 0;
    const bool hdiag = (qb < 64) && (wave == 3);
    const int nc = nrun + (hdiag ? 1 : 0);

#define CBASE(i) (((i) < nrun) ? (1024 + (wave + 4 * (i)) * 64) : (qb * 16))
#define CVALID(i) (((i) < nrun) ? (R - (wave + 4 * (i)) * 64) : 16)  // >=64 means full

    bf16x8 kc[4][2], kn[4][2];
    if (nc > 0) {
        const int b0 = CBASE(0);
#pragma unroll
        for (int n = 0; n < 4; ++n) {
            const ushort* Kp = Kb + (long)(b0 + n * 16) * 2304;
            kc[n][0] = *(const bf16x8*)Kp;
            kc[n][1] = *(const bf16x8*)(Kp + 32);
        }
    }
    for (int i = 0; i < nc; ++i) {
        const int base = CBASE(i);
        const int valid = min(64, CVALID(i));
        // early-issue V for this chunk
        bf16x8 vf[4][2];
#pragma unroll
        for (int dt = 0; dt < 4; ++dt) {
            const ushort* Vp = Vbs + (long)(dt * 16) * SEQ + base;
            vf[dt][0] = *(const bf16x8*)Vp;
            vf[dt][1] = *(const bf16x8*)(Vp + 32);
        }
        // early-issue K for next chunk
        if (i + 1 < nc) {
            const int bn = CBASE(i + 1);
#pragma unroll
            for (int n = 0; n < 4; ++n) {
                const ushort* Kp = Kb + (long)(bn + n * 16) * 2304;
                kn[n][0] = *(const bf16x8*)Kp;
                kn[n][1] = *(const bf16x8*)(Kp + 32);
            }
        }
        // QK^T: lane (lo,hi) holds S[key=n*16+hi*4+g][q=lo]
        f32x4 s[4];
#pragma unroll
        for (int n = 0; n < 4; ++n) {
            f32x4 z = {};
            z = MFMA16x32(kc[n][0], qf0, z);
            z = MFMA16x32(kc[n][1], qf1, z);
            s[n] = z;
        }
        float p[4][4];
        float mx = -3.0e38f;
#pragma unroll
        for (int n = 0; n < 4; ++n)
#pragma unroll
            for (int g = 0; g < 4; ++g) {
                float v = (n * 16 + hi * 4 + g < valid) ? s[n][g] * 0.125f : -3.0e38f;
                p[n][g] = v;
                mx = fmaxf(mx, v);
            }
        mx = fmaxf(mx, __shfl_xor(mx, 16, 64));
        mx = fmaxf(mx, __shfl_xor(mx, 32, 64));
        float m_new = fmaxf(m_run, mx);
        float scale = __expf(m_run - m_new);
        float psum = 0.f;
#pragma unroll
        for (int n = 0; n < 4; ++n)
#pragma unroll
            for (int g = 0; g < 4; ++g) {
                float e = __expf(p[n][g] - m_new);  // masked -> exactly 0
                p[n][g] = e;
                psum += e;
            }
        psum += __shfl_xor(psum, 16, 64);
        psum += __shfl_xor(psum, 32, 64);
        l_run = l_run * scale + psum;
        m_run = m_new;
#pragma unroll
        for (int dt = 0; dt < 4; ++dt) oacc[dt] *= scale;
        // P -> bf16 pairs -> LDS row q=lo (128B rows, XOR-swizzled)
#pragma unroll
        for (int n = 0; n < 4; ++n)
#pragma unroll
            for (int pr = 0; pr < 2; ++pr) {
                uint32_t u = packbf2(p[n][pr * 2], p[n][pr * 2 + 1]);
                *(uint32_t*)(psb + lo * 128 + ((n * 32 + hi * 8 + pr * 4) ^ swz)) = u;
            }
        bf16x8 pa0 = *(const bf16x8*)(psb + lo * 128 + ((hi * 16) ^ swz));
        bf16x8 pa1 = *(const bf16x8*)(psb + lo * 128 + ((64 + hi * 16) ^ swz));
        // PV: masked keys have P == 0, so unconditional is exact
#pragma unroll
        for (int dt = 0; dt < 4; ++dt) {
            oacc[dt] = MFMA16x32(vf[dt][0], pa0, oacc[dt]);
            oacc[dt] = MFMA16x32(vf[dt][1], pa1, oacc[dt]);
        }
#pragma unroll
        for (int n = 0; n < 4; ++n) { kc[n][0] = kn[n][0]; kc[n][1] = kn[n][1]; }
    }
#undef CBASE
#undef CVALID

    // ---- merge the 4 wave-partials ----
#pragma unroll
    for (int dt = 0; dt < 4; ++dt)
#pragma unroll
        for (int g = 0; g < 4; ++g) lds_o[wave][dt * 16 + hi * 4 + g][lo] = oacc[dt][g];
    if (hi == 0) { lds_m[wave][lo] = m_run; lds_l[wave][lo] = l_run; }
    __syncthreads();
    float m0 = lds_m[0][lo], m1 = lds_m[1][lo], m2 = lds_m[2][lo], m3 = lds_m[3][lo];
    float mt = fmaxf(fmaxf(m0, m1), fmaxf(m2, m3));
    float f0 = __expf(m0 - mt), f1 = __expf(m1 - mt), f2 = __expf(m2 - mt), f3 = __expf(m3 - mt);
    float lt = lds_l[0][lo] * f0 + lds_l[1][lo] * f1 + lds_l[2][lo] * f2 + lds_l[3][lo] * f3;
    float inv = 1.f / lt;
    ushort4 st;
    float a0, a1c, a2, a3;
    {
        int d = wave * 16 + hi * 4;
        a0 = lds_o[0][d][lo] * f0 + lds_o[1][d][lo] * f1 + lds_o[2][d][lo] * f2 + lds_o[3][d][lo] * f3;
        a1c = lds_o[0][d + 1][lo] * f0 + lds_o[1][d + 1][lo] * f1 + lds_o[2][d + 1][lo] * f2 + lds_o[3][d + 1][lo] * f3;
        a2 = lds_o[0][d + 2][lo] * f0 + lds_o[1][d + 2][lo] * f1 + lds_o[2][d + 2][lo] * f2 + lds_o[3][d + 2][lo] * f3;
        a3 = lds_o[0][d + 3][lo] * f0 + lds_o[1][d + 3][lo] * f1 + lds_o[2][d + 3][lo] * f2 + lds_o[3][d + 3][lo] * f3;
    }
    st.x = f2bf(a0 * inv);
    st.y = f2bf(a1c * inv);
    st.z = f2bf(a2 * inv);
    st.w = f2bf(a3 * inv);
    *(ushort4*)&o[(row0 + lo) * DIM + head * 64 + wave * 16 + hi * 4] = st;
}

extern "C" void kernel_launch(void* const* d_in, const int* in_sizes, int n_in,
                              void* d_out, int out_size, void* d_ws, size_t ws_size,
                              hipStream_t stream) {
    const float* x      = (const float*)d_in[0];
    const float* cosT   = (const float*)d_in[1];
    const float* sinT   = (const float*)d_in[2];
    const float* c      = (const float*)d_in[3];
    const float* W_qkv  = (const float*)d_in[4];
    const float* W_out  = (const float*)d_in[5];
    const float* ln1_w  = (const float*)d_in[6];
    const float* ln2_w  = (const float*)d_in[7];
    const float* mlp_w1 = (const float*)d_in[8];
    const float* mlp_b1 = (const float*)d_in[9];
    const float* mlp_w2 = (const float*)d_in[10];
    const float* mlp_b2 = (const float*)d_in[11];
    const float* ada_w  = (const float*)d_in[12];
    const float* ada_b  = (const float*)d_in[13];
    float* out = (float*)d_out;

    char* ws = (char*)d_ws;
    float*  ada   = (float*)(ws + 0);
    ushort* h     = (ushort*)(ws + 65536L);
    ushort* qkv   = (ushort*)(ws + 6356992L);
    ushort* vt    = (ushort*)(ws + 25231360L);
    ushort* o     = (ushort*)(ws + 31522816L);
    float*  x1    = (float*)(ws + 37814272L);
    ushort* a1    = (ushort*)(ws + 50397184L);
    ushort* wqkvT = (ushort*)(ws + 75563008L);
    ushort* woutT = (ushort*)(ws + 79101952L);
    ushort* w1T   = (ushort*)(ws + 80281600L);
    ushort* w2T   = (ushort*)(ws + 85000192L);

    ada_kernel<<<dim3(18, 2), 256, 0, stream>>>(c, ada_w, ada_b, ada);
    convT<<<dim3(36, 12), 256, 0, stream>>>(W_qkv, wqkvT, 768, 2304);
    convT<<<dim3(12, 12), 256, 0, stream>>>(W_out, woutT, 768, 768);
    convT<<<dim3(48, 12), 256, 0, stream>>>(mlp_w1, w1T, 768, 3072);
    convT<<<dim3(12, 48), 256, 0, stream>>>(mlp_w2, w2T, 3072, 768);

    ln_mod_kernel<<<TOKENS, 256, 0, stream>>>(x, ln1_w, ada, 0, 768, h);
    gemm_bf16<0, 128><<<dim3(18, 32), 256, 0, stream>>>(h, wqkvT, qkv, TOKENS, 2304, 768,
                                                        nullptr, nullptr, nullptr, cosT, sinT);
    vtrans<<<dim3(32, 12, 2), 256, 0, stream>>>(qkv, vt);
    attn_mfma<<<dim3(128, 12, 2), 256, 0, stream>>>(qkv, vt, o);
    gemm_bf16<1, 64><<<dim3(6, 64), 256, 0, stream>>>(o, woutT, x1, TOKENS, 768, 768,
                                                      nullptr, ada + 1536, x, nullptr, nullptr);
    ln_mod_kernel<<<TOKENS, 256, 0, stream>>>(x1, ln2_w, ada, 2304, 3072, h);
    gemm_bf16<2, 128><<<dim3(24, 32), 256, 0, stream>>>(h, w1T, a1, TOKENS, DFF, 768,
                                                        mlp_b1, nullptr, nullptr, nullptr, nullptr);
    gemm_bf16<3, 64><<<dim3(6, 64), 256, 0, stream>>>(a1, w2T, out, TOKENS, 768, DFF,
                                                      mlp_b2, ada + 3840, x1, nullptr, nullptr);
}

// Round 7
// 353.493 us; speedup vs baseline: 1.0203x; 1.0203x over previous
//
#include <hip/hip_runtime.h>
#include <hip/hip_bf16.h>
#include <stdint.h>

#define DIM 768
#define SEQ 2048
#define TOKENS 4096
#define HEADS 12
#define DFF 3072
#define COND 128
#define ADA6 4608

typedef __attribute__((ext_vector_type(8))) short bf16x8;
typedef __attribute__((ext_vector_type(4))) float f32x4;

#define MFMA16x32(a, b, c) __builtin_amdgcn_mfma_f32_16x16x32_bf16(a, b, c, 0, 0, 0)
#define GLDS16(g, l)                                                                  \
    __builtin_amdgcn_global_load_lds((const __attribute__((address_space(1))) void*)(g), \
                                     (__attribute__((address_space(3))) void*)(l), 16, 0, 0)

__device__ __forceinline__ ushort f2bf(float f) {
    union { float f; uint32_t u; } v;
    v.f = f;
    uint32_t r = v.u + 0x7FFF + ((v.u >> 16) & 1);
    return (ushort)(r >> 16);
}

__device__ __forceinline__ uint32_t packbf2(float a, float b) {
    union { __hip_bfloat162 h; uint32_t u; } cv;
    cv.h = __float22bfloat162_rn(make_float2(a, b));
    return cv.u;
}

// ---------------- ada = c @ ada_w + ada_b  (2 x 4608, fp32) ----------------
__global__ void ada_kernel(const float* __restrict__ c, const float* __restrict__ ada_w,
                           const float* __restrict__ ada_b, float* __restrict__ ada) {
    int j = blockIdx.x * 256 + threadIdx.x;
    int bb = blockIdx.y;
    if (j < ADA6) {
        float acc = ada_b[j];
        for (int k = 0; k < COND; ++k)
            acc = fmaf(c[bb * COND + k], ada_w[(long)k * ADA6 + j], acc);
        ada[bb * ADA6 + j] = acc;
    }
}

// ------------- weight convert + transpose: W[K][N] f32 -> Wt[N][K] bf16 -------------
__global__ __launch_bounds__(256) void convT(const float* __restrict__ W,
                                             ushort* __restrict__ Wt, int K, int N) {
    __shared__ float t[64][65];
    int tid = threadIdx.x;
    int n0 = blockIdx.x * 64, k0 = blockIdx.y * 64;
#pragma unroll
    for (int it = 0; it < 4; ++it) {
        int idx = it * 256 + tid;
        int kr = idx >> 4, nc = (idx & 15) * 4;
        float4 v = *(const float4*)&W[(long)(k0 + kr) * N + n0 + nc];
        t[kr][nc] = v.x; t[kr][nc + 1] = v.y; t[kr][nc + 2] = v.z; t[kr][nc + 3] = v.w;
    }
    __syncthreads();
#pragma unroll
    for (int it = 0; it < 4; ++it) {
        int idx = it * 256 + tid;
        int nr = idx >> 4, kc = (idx & 15) * 4;
        ushort4 v;
        v.x = f2bf(t[kc][nr]); v.y = f2bf(t[kc + 1][nr]);
        v.z = f2bf(t[kc + 2][nr]); v.w = f2bf(t[kc + 3][nr]);
        *(ushort4*)&Wt[(long)(n0 + nr) * K + k0 + kc] = v;
    }
}

// ---------------- layernorm + adaLN modulate -> bf16 ----------------
__global__ __launch_bounds__(256) void ln_mod_kernel(const float* __restrict__ x,
                                                     const float* __restrict__ w,
                                                     const float* __restrict__ ada,
                                                     int shiftOff, int scaleOff,
                                                     ushort* __restrict__ out) {
    int token = blockIdx.x;
    int bb = token >> 11;
    int tid = threadIdx.x;
    const float* xi = x + (long)token * DIM;
    float v[3];
    float sum = 0.f, sumsq = 0.f;
#pragma unroll
    for (int t = 0; t < 3; ++t) {
        float val = xi[tid + 256 * t];
        v[t] = val;
        sum += val;
        sumsq = fmaf(val, val, sumsq);
    }
    for (int msk = 1; msk < 64; msk <<= 1) {
        sum += __shfl_xor(sum, msk, 64);
        sumsq += __shfl_xor(sumsq, msk, 64);
    }
    __shared__ float red0[4], red1[4];
    int wave = tid >> 6;
    if ((tid & 63) == 0) { red0[wave] = sum; red1[wave] = sumsq; }
    __syncthreads();
    sum = red0[0] + red0[1] + red0[2] + red0[3];
    sumsq = red1[0] + red1[1] + red1[2] + red1[3];
    float mu = sum * (1.f / DIM);
    float var = sumsq * (1.f / DIM) - mu * mu;
    float rs = rsqrtf(var + 1e-5f);
    const float* sh = ada + bb * ADA6 + shiftOff;
    const float* sc = ada + bb * ADA6 + scaleOff;
    ushort* oi = out + (long)token * DIM;
#pragma unroll
    for (int t = 0; t < 3; ++t) {
        int j = tid + 256 * t;
        oi[j] = f2bf((v[t] - mu) * rs * w[j] * (1.f + sc[j]) + sh[j]);
    }
}

// ---------------- bf16 MFMA GEMM, BMx128 tile, BK=64, 4 waves ----------------
// A[M][K] bf16 row-major, B = Wt[N][K] bf16 row-major.  C = A @ Wt^T.
// EPI 0: rope -> bf16 (qkv); 1: gate*acc+skip -> f32; 2: gelu(acc+bias) -> bf16;
// EPI 3: gate*(acc+bias)+skip -> f32
template <int EPI, int BM>
__global__ __launch_bounds__(256) void gemm_bf16(const ushort* __restrict__ A,
                                                 const ushort* __restrict__ B,
                                                 void* __restrict__ Cp, int M, int N, int K,
                                                 const float* __restrict__ bias,
                                                 const float* __restrict__ gate,
                                                 const float* __restrict__ skip,
                                                 const float* __restrict__ cosT,
                                                 const float* __restrict__ sinT) {
    constexpr int MR = BM / 32;  // frags per wave in M
    __shared__ ushort As[BM * 64];
    __shared__ ushort Bs[128 * 64];
    const int tid = threadIdx.x;
    const int wave = tid >> 6, lane = tid & 63;
    const int lo = lane & 15, hi = lane >> 4;
    const int wr = wave >> 1, wc = wave & 1;
    const int row0 = blockIdx.y * BM, col0 = blockIdx.x * 128;
    const int srow = tid >> 3;       // 0..31
    const int scol = (tid & 7) * 8;  // k elems
    f32x4 acc[MR][4] = {};
    const long astep = (long)32 * K;
    const ushort* Ag = A + (long)(row0 + srow) * K + scol;
    const ushort* Bg = B + (long)(col0 + srow) * K + scol;
    for (int k0 = 0; k0 < K; k0 += 64) {
        __syncthreads();
#pragma unroll
        for (int t = 0; t < MR; ++t)
            GLDS16(Ag + t * astep + k0, (char*)As + (t * 256 + tid) * 16);
#pragma unroll
        for (int t = 0; t < 4; ++t)
            GLDS16(Bg + t * astep + k0, (char*)Bs + (t * 256 + tid) * 16);
        __syncthreads();
#pragma unroll
        for (int kk = 0; kk < 2; ++kk) {
            bf16x8 af[MR], bfr[4];
#pragma unroll
            for (int m = 0; m < MR; ++m)
                af[m] = *(const bf16x8*)&As[(wr * (BM / 2) + m * 16 + lo) * 64 + kk * 32 + hi * 8];
#pragma unroll
            for (int n = 0; n < 4; ++n)
                bfr[n] = *(const bf16x8*)&Bs[(wc * 64 + n * 16 + lo) * 64 + kk * 32 + hi * 8];
#pragma unroll
            for (int m = 0; m < MR; ++m)
#pragma unroll
                for (int n = 0; n < 4; ++n)
                    acc[m][n] = MFMA16x32(af[m], bfr[n], acc[m][n]);
        }
    }
    // epilogue: lane holds C[row0+wr*(BM/2)+m*16+hi*4+reg][col0+wc*64+n*16+lo]
    if (EPI == 0) {
        ushort* C = (ushort*)Cp;
#pragma unroll
        for (int m = 0; m < MR; ++m)
#pragma unroll
            for (int reg = 0; reg < 4; ++reg) {
                int r = row0 + wr * (BM / 2) + m * 16 + hi * 4 + reg;
                int pos = r & 1023;
                const float* cb = cosT + pos * 64;
                const float* sb = sinT + pos * 64;
                long rb = (long)r * N + col0 + wc * 64;
#pragma unroll
                for (int pr = 0; pr < 2; ++pr) {
                    int i = pr * 16 + lo;
                    float v0 = acc[m][pr][reg], v1 = acc[m][pr + 2][reg];
                    float c0 = cb[i], s0 = sb[i], c1 = cb[i + 32], s1 = sb[i + 32];
                    C[rb + i] = f2bf(v0 * c0 - v1 * s0);
                    C[rb + i + 32] = f2bf(v1 * c1 + v0 * s1);
                }
            }
    } else if (EPI == 1) {
        float* C = (float*)Cp;
#pragma unroll
        for (int m = 0; m < MR; ++m)
#pragma unroll
            for (int reg = 0; reg < 4; ++reg) {
                int r = row0 + wr * (BM / 2) + m * 16 + hi * 4 + reg;
                int bbi = r >> 11;
#pragma unroll
                for (int n = 0; n < 4; ++n) {
                    int c = col0 + wc * 64 + n * 16 + lo;
                    C[(long)r * N + c] =
                        gate[bbi * ADA6 + c] * acc[m][n][reg] + skip[(long)r * DIM + c];
                }
            }
    } else if (EPI == 2) {
        ushort* C = (ushort*)Cp;
#pragma unroll
        for (int m = 0; m < MR; ++m)
#pragma unroll
            for (int reg = 0; reg < 4; ++reg) {
                int r = row0 + wr * (BM / 2) + m * 16 + hi * 4 + reg;
#pragma unroll
                for (int n = 0; n < 4; ++n) {
                    int c = col0 + wc * 64 + n * 16 + lo;
                    float v = acc[m][n][reg] + bias[c];
                    float g = v / (1.f + __expf(-1.5957691216f * (v + 0.044715f * v * v * v)));
                    C[(long)r * N + c] = f2bf(g);
                }
            }
    } else {
        float* C = (float*)Cp;
#pragma unroll
        for (int m = 0; m < MR; ++m)
#pragma unroll
            for (int reg = 0; reg < 4; ++reg) {
                int r = row0 + wr * (BM / 2) + m * 16 + hi * 4 + reg;
                int bbi = r >> 11;
#pragma unroll
                for (int n = 0; n < 4; ++n) {
                    int c = col0 + wc * 64 + n * 16 + lo;
                    C[(long)r * N + c] = gate[bbi * ADA6 + c] * (acc[m][n][reg] + bias[c]) +
                                         skip[(long)r * DIM + c];
                }
            }
    }
}

// ------------- V transpose: qkv[tok][1536+h*64+d] -> vt[(bb*12+h)*64+d][tok] -------------
__global__ __launch_bounds__(256) void vtrans(const ushort* __restrict__ qkv,
                                              ushort* __restrict__ vt) {
    __shared__ ushort t[64][65];
    int tid = threadIdx.x;
    int tb = blockIdx.x;
    int head = blockIdx.y;
    int bb = blockIdx.z;
#pragma unroll
    for (int it = 0; it < 4; ++it) {
        int idx = it * 256 + tid;
        int tok = idx >> 4, d4 = (idx & 15) * 4;
        const ushort* p = qkv + ((long)bb * SEQ + tb * 64 + tok) * 2304 + 1536 + head * 64 + d4;
        ushort4 v = *(const ushort4*)p;
        t[tok][d4] = v.x; t[tok][d4 + 1] = v.y; t[tok][d4 + 2] = v.z; t[tok][d4 + 3] = v.w;
    }
    __syncthreads();
#pragma unroll
    for (int it = 0; it < 4; ++it) {
        int idx = it * 256 + tid;
        int d = idx >> 4, t4 = (idx & 15) * 4;
        ushort4 v;
        v.x = t[t4][d]; v.y = t[t4 + 1][d]; v.z = t[t4 + 2][d]; v.w = t[t4 + 3][d];
        *(ushort4*)&vt[((long)(bb * HEADS + head) * 64 + d) * SEQ + tb * 64 + t4] = v;
    }
}

// ---------------- MFMA flash attention: split-KV, KVBLK=128 ----------------
// grid (128 qb, 12 heads, 2 bb), 256 thr. 4 waves share (qb, head); wave w takes
// 128-key chunks w, w+4, ... of the second-half run; wave 3 adds the 16-key diag.
// QK^T as mfma(K,Q): lane (lo,hi) holds S[key=n*16+hi*4+g][q=lo].
// PV as mfma(Vt,P): lane holds O[d=dt*16+hi*4+g][q=lo]. Partials merged via LDS.
__global__ __launch_bounds__(256, 3) void attn_mfma(const ushort* __restrict__ qkv,
                                                    const ushort* __restrict__ vt,
                                                    ushort* __restrict__ o) {
    __shared__ char ps[4 * 4096];  // per-wave P buffer: 16 rows x 256 B
    __shared__ float lds_m[4][16], lds_l[4][16];
    __shared__ float lds_o[4][64][16];
    const int tid = threadIdx.x;
    const int wave = tid >> 6, lane = tid & 63;
    const int lo = lane & 15, hi = lane >> 4;
    const int bx = blockIdx.x;
    const int qb = (bx & 1) ? (63 - (bx >> 1)) : (127 - (bx >> 1));  // heavy first
    const int head = blockIdx.y;
    const int bb = blockIdx.z;
    char* psb = ps + wave * 4096;
    const int swz = (lo & 7) << 4;
    const long row0 = (long)bb * SEQ + qb * 16;
    const ushort* Qp = qkv + (row0 + lo) * 2304 + head * 64 + hi * 8;
    bf16x8 qf0 = *(const bf16x8*)Qp;
    bf16x8 qf1 = *(const bf16x8*)(Qp + 32);
    f32x4 oacc[4] = {};
    float m_run = -3.0e38f, l_run = 0.f;
    const ushort* Kb = qkv + ((long)bb * SEQ + lo) * 2304 + DIM + head * 64 + hi * 8;
    const ushort* Vbs = vt + ((long)(bb * HEADS + head) * 64 + lo) * SEQ + hi * 8;

    const int R = (qb < 64) ? qb * 16 : (qb - 63) * 16;  // second-half run length
    const int Rc = (R + 127) >> 7;                       // 128-key chunks

    for (int c = wave; c < Rc; c += 4) {
        const int base = 1024 + c * 128;
        const int valid = min(128, R - c * 128);
        // K loads (freed after QK)
        bf16x8 kf[8][2];
#pragma unroll
        for (int n = 0; n < 8; ++n) {
            const ushort* Kp = Kb + (long)(base + n * 16) * 2304;
            kf[n][0] = *(const bf16x8*)Kp;
            kf[n][1] = *(const bf16x8*)(Kp + 32);
        }
        f32x4 s[8];
#pragma unroll
        for (int n = 0; n < 8; ++n) {
            f32x4 z = {};
            z = MFMA16x32(kf[n][0], qf0, z);
            z = MFMA16x32(kf[n][1], qf1, z);
            s[n] = z;
        }
        // V issue early: latency hides under softmax + LDS transpose
        bf16x8 vf[4][4];
#pragma unroll
        for (int dt = 0; dt < 4; ++dt)
#pragma unroll
            for (int g = 0; g < 4; ++g)
                vf[dt][g] = *(const bf16x8*)(Vbs + (long)(dt * 16) * SEQ + base + g * 32);
        // softmax (lane owns q=lo; keys n*16+hi*4+g; reduce across hi lanes)
        float p[8][4];
        float mx = -3.0e38f;
#pragma unroll
        for (int n = 0; n < 8; ++n)
#pragma unroll
            for (int g = 0; g < 4; ++g) {
                float v = (n * 16 + hi * 4 + g < valid) ? s[n][g] * 0.125f : -3.0e38f;
                p[n][g] = v;
                mx = fmaxf(mx, v);
            }
        mx = fmaxf(mx, __shfl_xor(mx, 16, 64));
        mx = fmaxf(mx, __shfl_xor(mx, 32, 64));
        float m_new = fmaxf(m_run, mx);
        float scale = __expf(m_run - m_new);
        float psum = 0.f;
#pragma unroll
        for (int n = 0; n < 8; ++n)
#pragma unroll
            for (int g = 0; g < 4; ++g) {
                float e = __expf(p[n][g] - m_new);  // masked -> exactly 0
                p[n][g] = e;
                psum += e;
            }
        psum += __shfl_xor(psum, 16, 64);
        psum += __shfl_xor(psum, 32, 64);
        l_run = l_run * scale + psum;
        m_run = m_new;
#pragma unroll
        for (int dt = 0; dt < 4; ++dt) oacc[dt] *= scale;
        // P -> bf16 pairs -> LDS row q=lo (256B rows, XOR-swizzled)
#pragma unroll
        for (int n = 0; n < 8; ++n)
#pragma unroll
            for (int pr = 0; pr < 2; ++pr) {
                uint32_t u = packbf2(p[n][pr * 2], p[n][pr * 2 + 1]);
                *(uint32_t*)(psb + lo * 256 + ((n * 32 + hi * 8 + pr * 4) ^ swz)) = u;
            }
        bf16x8 pa[4];
#pragma unroll
        for (int g = 0; g < 4; ++g)
            pa[g] = *(const bf16x8*)(psb + lo * 256 + ((g * 64 + hi * 16) ^ swz));
        // PV (masked keys have P == 0 -> exact)
#pragma unroll
        for (int dt = 0; dt < 4; ++dt)
#pragma unroll
            for (int g = 0; g < 4; ++g)
                oacc[dt] = MFMA16x32(vf[dt][g], pa[g], oacc[dt]);
    }

    // diagonal 16-key block (qb<64), quarter-chunk on wave 3
    if (qb < 64 && wave == 3) {
        const int base = qb * 16;
        const ushort* Kp = Kb + (long)base * 2304;
        bf16x8 kf0 = *(const bf16x8*)Kp;
        bf16x8 kf1 = *(const bf16x8*)(Kp + 32);
        f32x4 z = {};
        z = MFMA16x32(kf0, qf0, z);
        z = MFMA16x32(kf1, qf1, z);
        bf16x8 vd[4];
#pragma unroll
        for (int dt = 0; dt < 4; ++dt)
            vd[dt] = *(const bf16x8*)(Vbs + (long)(dt * 16) * SEQ + base);
        float p[4];
        float mx = -3.0e38f;
#pragma unroll
        for (int g = 0; g < 4; ++g) {
            p[g] = z[g] * 0.125f;  // all 16 keys valid
            mx = fmaxf(mx, p[g]);
        }
        mx = fmaxf(mx, __shfl_xor(mx, 16, 64));
        mx = fmaxf(mx, __shfl_xor(mx, 32, 64));
        float m_new = fmaxf(m_run, mx);
        float scale = __expf(m_run - m_new);
        float psum = 0.f;
#pragma unroll
        for (int g = 0; g < 4; ++g) {
            float e = __expf(p[g] - m_new);
            p[g] = e;
            psum += e;
        }
        psum += __shfl_xor(psum, 16, 64);
        psum += __shfl_xor(psum, 32, 64);
        l_run = l_run * scale + psum;
        m_run = m_new;
#pragma unroll
        for (int dt = 0; dt < 4; ++dt) oacc[dt] *= scale;
#pragma unroll
        for (int pr = 0; pr < 2; ++pr) {
            *(uint32_t*)(psb + lo * 256 + ((hi * 8 + pr * 4) ^ swz)) =
                packbf2(p[pr * 2], p[pr * 2 + 1]);
            *(uint32_t*)(psb + lo * 256 + ((32 + hi * 8 + pr * 4) ^ swz)) = 0;  // keys 16-31
        }
        bf16x8 pa0 = *(const bf16x8*)(psb + lo * 256 + ((hi * 16) ^ swz));
#pragma unroll
        for (int dt = 0; dt < 4; ++dt) oacc[dt] = MFMA16x32(vd[dt], pa0, oacc[dt]);
    }

    // ---- merge the 4 wave-partials ----
#pragma unroll
    for (int dt = 0; dt < 4; ++dt)
#pragma unroll
        for (int g = 0; g < 4; ++g) lds_o[wave][dt * 16 + hi * 4 + g][lo] = oacc[dt][g];
    if (hi == 0) { lds_m[wave][lo] = m_run; lds_l[wave][lo] = l_run; }
    __syncthreads();
    float m0 = lds_m[0][lo], m1 = lds_m[1][lo], m2 = lds_m[2][lo], m3 = lds_m[3][lo];
    float mt = fmaxf(fmaxf(m0, m1), fmaxf(m2, m3));
    float f0 = __expf(m0 - mt), f1 = __expf(m1 - mt), f2 = __expf(m2 - mt), f3 = __expf(m3 - mt);
    float lt = lds_l[0][lo] * f0 + lds_l[1][lo] * f1 + lds_l[2][lo] * f2 + lds_l[3][lo] * f3;
    float inv = 1.f / lt;
    ushort4 st;
    float a0, a1c, a2, a3;
    {
        int d = wave * 16 + hi * 4;
        a0 = lds_o[0][d][lo] * f0 + lds_o[1][d][lo] * f1 + lds_o[2][d][lo] * f2 + lds_o[3][d][lo] * f3;
        a1c = lds_o[0][d + 1][lo] * f0 + lds_o[1][d + 1][lo] * f1 + lds_o[2][d + 1][lo] * f2 + lds_o[3][d + 1][lo] * f3;
        a2 = lds_o[0][d + 2][lo] * f0 + lds_o[1][d + 2][lo] * f1 + lds_o[2][d + 2][lo] * f2 + lds_o[3][d + 2][lo] * f3;
        a3 = lds_o[0][d + 3][lo] * f0 + lds_o[1][d + 3][lo] * f1 + lds_o[2][d + 3][lo] * f2 + lds_o[3][d + 3][lo] * f3;
    }
    st.x = f2bf(a0 * inv);
    st.y = f2bf(a1c * inv);
    st.z = f2bf(a2 * inv);
    st.w = f2bf(a3 * inv);
    *(ushort4*)&o[(row0 + lo) * DIM + head * 64 + wave * 16 + hi * 4] = st;
}

extern "C" void kernel_launch(void* const* d_in, const int* in_sizes, int n_in,
                              void* d_out, int out_size, void* d_ws, size_t ws_size,
                              hipStream_t stream) {
    const float* x      = (const float*)d_in[0];
    const float* cosT   = (const float*)d_in[1];
    const float* sinT   = (const float*)d_in[2];
    const float* c      = (const float*)d_in[3];
    const float* W_qkv  = (const float*)d_in[4];
    const float* W_out  = (const float*)d_in[5];
    const float* ln1_w  = (const float*)d_in[6];
    const float* ln2_w  = (const float*)d_in[7];
    const float* mlp_w1 = (const float*)d_in[8];
    const float* mlp_b1 = (const float*)d_in[9];
    const float* mlp_w2 = (const float*)d_in[10];
    const float* mlp_b2 = (const float*)d_in[11];
    const float* ada_w  = (const float*)d_in[12];
    const float* ada_b  = (const float*)d_in[13];
    float* out = (float*)d_out;

    char* ws = (char*)d_ws;
    float*  ada   = (float*)(ws + 0);
    ushort* h     = (ushort*)(ws + 65536L);
    ushort* qkv   = (ushort*)(ws + 6356992L);
    ushort* vt    = (ushort*)(ws + 25231360L);
    ushort* o     = (ushort*)(ws + 31522816L);
    float*  x1    = (float*)(ws + 37814272L);
    ushort* a1    = (ushort*)(ws + 50397184L);
    ushort* wqkvT = (ushort*)(ws + 75563008L);
    ushort* woutT = (ushort*)(ws + 79101952L);
    ushort* w1T   = (ushort*)(ws + 80281600L);
    ushort* w2T   = (ushort*)(ws + 85000192L);

    ada_kernel<<<dim3(18, 2), 256, 0, stream>>>(c, ada_w, ada_b, ada);
    convT<<<dim3(36, 12), 256, 0, stream>>>(W_qkv, wqkvT, 768, 2304);
    convT<<<dim3(12, 12), 256, 0, stream>>>(W_out, woutT, 768, 768);
    convT<<<dim3(48, 12), 256, 0, stream>>>(mlp_w1, w1T, 768, 3072);
    convT<<<dim3(12, 48), 256, 0, stream>>>(mlp_w2, w2T, 3072, 768);

    ln_mod_kernel<<<TOKENS, 256, 0, stream>>>(x, ln1_w, ada, 0, 768, h);
    gemm_bf16<0, 128><<<dim3(18, 32), 256, 0, stream>>>(h, wqkvT, qkv, TOKENS, 2304, 768,
                                                        nullptr, nullptr, nullptr, cosT, sinT);
    vtrans<<<dim3(32, 12, 2), 256, 0, stream>>>(qkv, vt);
    attn_mfma<<<dim3(128, 12, 2), 256, 0, stream>>>(qkv, vt, o);
    gemm_bf16<1, 64><<<dim3(6, 64), 256, 0, stream>>>(o, woutT, x1, TOKENS, 768, 768,
                                                      nullptr, ada + 1536, x, nullptr, nullptr);
    ln_mod_kernel<<<TOKENS, 256, 0, stream>>>(x1, ln2_w, ada, 2304, 3072, h);
    gemm_bf16<2, 128><<<dim3(24, 32), 256, 0, stream>>>(h, w1T, a1, TOKENS, DFF, 768,
                                                        mlp_b1, nullptr, nullptr, nullptr, nullptr);
    gemm_bf16<3, 64><<<dim3(6, 64), 256, 0, stream>>>(a1, w2T, out, TOKENS, 768, DFF,
                                                      mlp_b2, ada + 3840, x1, nullptr, nullptr);
}

// Round 8
// 327.494 us; speedup vs baseline: 1.1013x; 1.0794x over previous
//
#include <hip/hip_runtime.h>
#include <hip/hip_bf16.h>
#include <stdint.h>

#define DIM 768
#define SEQ 2048
#define TOKENS 4096
#define HEADS 12
#define DFF 3072
#define COND 128
#define ADA6 4608

typedef __attribute__((ext_vector_type(8))) short bf16x8;
typedef __attribute__((ext_vector_type(4))) float f32x4;

#define MFMA16x32(a, b, c) __builtin_amdgcn_mfma_f32_16x16x32_bf16(a, b, c, 0, 0, 0)
#define GLDS16(g, l)                                                                  \
    __builtin_amdgcn_global_load_lds((const __attribute__((address_space(1))) void*)(g), \
                                     (__attribute__((address_space(3))) void*)(l), 16, 0, 0)

__device__ __forceinline__ ushort f2bf(float f) {
    union { float f; uint32_t u; } v;
    v.f = f;
    uint32_t r = v.u + 0x7FFF + ((v.u >> 16) & 1);
    return (ushort)(r >> 16);
}

__device__ __forceinline__ uint32_t packbf2(float a, float b) {
    union { __hip_bfloat162 h; uint32_t u; } cv;
    cv.h = __float22bfloat162_rn(make_float2(a, b));
    return cv.u;
}

// ---------------- ada = c @ ada_w + ada_b  (2 x 4608, fp32) ----------------
__global__ void ada_kernel(const float* __restrict__ c, const float* __restrict__ ada_w,
                           const float* __restrict__ ada_b, float* __restrict__ ada) {
    int j = blockIdx.x * 256 + threadIdx.x;
    int bb = blockIdx.y;
    if (j < ADA6) {
        float acc = ada_b[j];
        for (int k = 0; k < COND; ++k)
            acc = fmaf(c[bb * COND + k], ada_w[(long)k * ADA6 + j], acc);
        ada[bb * ADA6 + j] = acc;
    }
}

// ------------- weight convert + transpose: W[K][N] f32 -> Wt[N][K] bf16 -------------
__global__ __launch_bounds__(256) void convT(const float* __restrict__ W,
                                             ushort* __restrict__ Wt, int K, int N) {
    __shared__ float t[64][65];
    int tid = threadIdx.x;
    int n0 = blockIdx.x * 64, k0 = blockIdx.y * 64;
#pragma unroll
    for (int it = 0; it < 4; ++it) {
        int idx = it * 256 + tid;
        int kr = idx >> 4, nc = (idx & 15) * 4;
        float4 v = *(const float4*)&W[(long)(k0 + kr) * N + n0 + nc];
        t[kr][nc] = v.x; t[kr][nc + 1] = v.y; t[kr][nc + 2] = v.z; t[kr][nc + 3] = v.w;
    }
    __syncthreads();
#pragma unroll
    for (int it = 0; it < 4; ++it) {
        int idx = it * 256 + tid;
        int nr = idx >> 4, kc = (idx & 15) * 4;
        ushort4 v;
        v.x = f2bf(t[kc][nr]); v.y = f2bf(t[kc + 1][nr]);
        v.z = f2bf(t[kc + 2][nr]); v.w = f2bf(t[kc + 3][nr]);
        *(ushort4*)&Wt[(long)(n0 + nr) * K + k0 + kc] = v;
    }
}

// ---------------- layernorm + adaLN modulate -> bf16 ----------------
__global__ __launch_bounds__(256) void ln_mod_kernel(const float* __restrict__ x,
                                                     const float* __restrict__ w,
                                                     const float* __restrict__ ada,
                                                     int shiftOff, int scaleOff,
                                                     ushort* __restrict__ out) {
    int token = blockIdx.x;
    int bb = token >> 11;
    int tid = threadIdx.x;
    const float* xi = x + (long)token * DIM;
    float v[3];
    float sum = 0.f, sumsq = 0.f;
#pragma unroll
    for (int t = 0; t < 3; ++t) {
        float val = xi[tid + 256 * t];
        v[t] = val;
        sum += val;
        sumsq = fmaf(val, val, sumsq);
    }
    for (int msk = 1; msk < 64; msk <<= 1) {
        sum += __shfl_xor(sum, msk, 64);
        sumsq += __shfl_xor(sumsq, msk, 64);
    }
    __shared__ float red0[4], red1[4];
    int wave = tid >> 6;
    if ((tid & 63) == 0) { red0[wave] = sum; red1[wave] = sumsq; }
    __syncthreads();
    sum = red0[0] + red0[1] + red0[2] + red0[3];
    sumsq = red1[0] + red1[1] + red1[2] + red1[3];
    float mu = sum * (1.f / DIM);
    float var = sumsq * (1.f / DIM) - mu * mu;
    float rs = rsqrtf(var + 1e-5f);
    const float* sh = ada + bb * ADA6 + shiftOff;
    const float* sc = ada + bb * ADA6 + scaleOff;
    ushort* oi = out + (long)token * DIM;
#pragma unroll
    for (int t = 0; t < 3; ++t) {
        int j = tid + 256 * t;
        oi[j] = f2bf((v[t] - mu) * rs * w[j] * (1.f + sc[j]) + sh[j]);
    }
}

// ---------------- bf16 MFMA GEMM, BMx128 tile, BK=64, 4 waves ----------------
// A[M][K] bf16 row-major, B = Wt[N][K] bf16 row-major.  C = A @ Wt^T.
// EPI 0: rope -> bf16 (qkv); 1: gate*acc+skip -> f32; 2: gelu(acc+bias) -> bf16;
// EPI 3: gate*(acc+bias)+skip -> f32
template <int EPI, int BM>
__global__ __launch_bounds__(256) void gemm_bf16(const ushort* __restrict__ A,
                                                 const ushort* __restrict__ B,
                                                 void* __restrict__ Cp, int M, int N, int K,
                                                 const float* __restrict__ bias,
                                                 const float* __restrict__ gate,
                                                 const float* __restrict__ skip,
                                                 const float* __restrict__ cosT,
                                                 const float* __restrict__ sinT) {
    constexpr int MR = BM / 32;  // frags per wave in M
    __shared__ ushort As[BM * 64];
    __shared__ ushort Bs[128 * 64];
    const int tid = threadIdx.x;
    const int wave = tid >> 6, lane = tid & 63;
    const int lo = lane & 15, hi = lane >> 4;
    const int wr = wave >> 1, wc = wave & 1;
    const int row0 = blockIdx.y * BM, col0 = blockIdx.x * 128;
    const int srow = tid >> 3;       // 0..31
    const int scol = (tid & 7) * 8;  // k elems
    f32x4 acc[MR][4] = {};
    const long astep = (long)32 * K;
    const ushort* Ag = A + (long)(row0 + srow) * K + scol;
    const ushort* Bg = B + (long)(col0 + srow) * K + scol;
    for (int k0 = 0; k0 < K; k0 += 64) {
        __syncthreads();
#pragma unroll
        for (int t = 0; t < MR; ++t)
            GLDS16(Ag + t * astep + k0, (char*)As + (t * 256 + tid) * 16);
#pragma unroll
        for (int t = 0; t < 4; ++t)
            GLDS16(Bg + t * astep + k0, (char*)Bs + (t * 256 + tid) * 16);
        __syncthreads();
#pragma unroll
        for (int kk = 0; kk < 2; ++kk) {
            bf16x8 af[MR], bfr[4];
#pragma unroll
            for (int m = 0; m < MR; ++m)
                af[m] = *(const bf16x8*)&As[(wr * (BM / 2) + m * 16 + lo) * 64 + kk * 32 + hi * 8];
#pragma unroll
            for (int n = 0; n < 4; ++n)
                bfr[n] = *(const bf16x8*)&Bs[(wc * 64 + n * 16 + lo) * 64 + kk * 32 + hi * 8];
#pragma unroll
            for (int m = 0; m < MR; ++m)
#pragma unroll
                for (int n = 0; n < 4; ++n)
                    acc[m][n] = MFMA16x32(af[m], bfr[n], acc[m][n]);
        }
    }
    // epilogue: lane holds C[row0+wr*(BM/2)+m*16+hi*4+reg][col0+wc*64+n*16+lo]
    if (EPI == 0) {
        ushort* C = (ushort*)Cp;
#pragma unroll
        for (int m = 0; m < MR; ++m)
#pragma unroll
            for (int reg = 0; reg < 4; ++reg) {
                int r = row0 + wr * (BM / 2) + m * 16 + hi * 4 + reg;
                int pos = r & 1023;
                const float* cb = cosT + pos * 64;
                const float* sb = sinT + pos * 64;
                long rb = (long)r * N + col0 + wc * 64;
#pragma unroll
                for (int pr = 0; pr < 2; ++pr) {
                    int i = pr * 16 + lo;
                    float v0 = acc[m][pr][reg], v1 = acc[m][pr + 2][reg];
                    float c0 = cb[i], s0 = sb[i], c1 = cb[i + 32], s1 = sb[i + 32];
                    C[rb + i] = f2bf(v0 * c0 - v1 * s0);
                    C[rb + i + 32] = f2bf(v1 * c1 + v0 * s1);
                }
            }
    } else if (EPI == 1) {
        float* C = (float*)Cp;
#pragma unroll
        for (int m = 0; m < MR; ++m)
#pragma unroll
            for (int reg = 0; reg < 4; ++reg) {
                int r = row0 + wr * (BM / 2) + m * 16 + hi * 4 + reg;
                int bbi = r >> 11;
#pragma unroll
                for (int n = 0; n < 4; ++n) {
                    int c = col0 + wc * 64 + n * 16 + lo;
                    C[(long)r * N + c] =
                        gate[bbi * ADA6 + c] * acc[m][n][reg] + skip[(long)r * DIM + c];
                }
            }
    } else if (EPI == 2) {
        ushort* C = (ushort*)Cp;
#pragma unroll
        for (int m = 0; m < MR; ++m)
#pragma unroll
            for (int reg = 0; reg < 4; ++reg) {
                int r = row0 + wr * (BM / 2) + m * 16 + hi * 4 + reg;
#pragma unroll
                for (int n = 0; n < 4; ++n) {
                    int c = col0 + wc * 64 + n * 16 + lo;
                    float v = acc[m][n][reg] + bias[c];
                    float g = v / (1.f + __expf(-1.5957691216f * (v + 0.044715f * v * v * v)));
                    C[(long)r * N + c] = f2bf(g);
                }
            }
    } else {
        float* C = (float*)Cp;
#pragma unroll
        for (int m = 0; m < MR; ++m)
#pragma unroll
            for (int reg = 0; reg < 4; ++reg) {
                int r = row0 + wr * (BM / 2) + m * 16 + hi * 4 + reg;
                int bbi = r >> 11;
#pragma unroll
                for (int n = 0; n < 4; ++n) {
                    int c = col0 + wc * 64 + n * 16 + lo;
                    C[(long)r * N + c] = gate[bbi * ADA6 + c] * (acc[m][n][reg] + bias[c]) +
                                         skip[(long)r * DIM + c];
                }
            }
    }
}

// ------------- V transpose: qkv[tok][1536+h*64+d] -> vt[(bb*12+h)*64+d][tok] -------------
__global__ __launch_bounds__(256) void vtrans(const ushort* __restrict__ qkv,
                                              ushort* __restrict__ vt) {
    __shared__ ushort t[64][65];
    int tid = threadIdx.x;
    int tb = blockIdx.x;
    int head = blockIdx.y;
    int bb = blockIdx.z;
#pragma unroll
    for (int it = 0; it < 4; ++it) {
        int idx = it * 256 + tid;
        int tok = idx >> 4, d4 = (idx & 15) * 4;
        const ushort* p = qkv + ((long)bb * SEQ + tb * 64 + tok) * 2304 + 1536 + head * 64 + d4;
        ushort4 v = *(const ushort4*)p;
        t[tok][d4] = v.x; t[tok][d4 + 1] = v.y; t[tok][d4 + 2] = v.z; t[tok][d4 + 3] = v.w;
    }
    __syncthreads();
#pragma unroll
    for (int it = 0; it < 4; ++it) {
        int idx = it * 256 + tid;
        int d = idx >> 4, t4 = (idx & 15) * 4;
        ushort4 v;
        v.x = t[t4][d]; v.y = t[t4 + 1][d]; v.z = t[t4 + 2][d]; v.w = t[t4 + 3][d];
        *(ushort4*)&vt[((long)(bb * HEADS + head) * 64 + d) * SEQ + tb * 64 + t4] = v;
    }
}

// ---------------- MFMA flash attention: shared-KV LDS, 2-phase pipeline ----------------
// grid (32 tiles, 12 heads, 2 bb), 256 thr. Block = 64 q rows (4 qblocks); wave w owns
// qblock tile*4+w (rows tile*64+w*16..+16). All waves share each 64-key chunk, staged
// into double-buffered LDS via global_load_lds (linear dest, inverse-swizzled source,
// swizzled reads). Counted vmcnt(4) + raw s_barrier (T3 2-phase).
// Chunks: c<ncausal -> keys [1024+c*64); first-half tiles add diag chunk keys [tile*64).
// QK as mfma(K,Q): lane (lo,hi) holds S[key=n*16+hi*4+g][q=lo]; per-lane softmax (q=lo).
// PV as mfma(Vt,P): lane holds O[d=dt*16+hi*4+g][q=lo].
__global__ __launch_bounds__(256) void attn_mfma(const ushort* __restrict__ qkv,
                                                 const ushort* __restrict__ vt,
                                                 ushort* __restrict__ o) {
    __shared__ ushort Ks[2][4096];  // [64 key][64 d], rows XOR-swizzled by (row&7)
    __shared__ ushort Vs[2][4096];  // [64 d][64 key], same swizzle
    __shared__ char ps[4][2048];    // per-wave P: 16 q rows x 128 B
    const int tid = threadIdx.x;
    const int wave = tid >> 6, lane = tid & 63;
    const int lo = lane & 15, hi = lane >> 4;
    const int bx = blockIdx.x;
    const int tile = (bx & 1) ? (31 - (bx >> 1)) : (15 - (bx >> 1));  // heavy first
    const int head = blockIdx.y;
    const int bb = blockIdx.z;
    char* psb = ps[wave];
    const int swz = (lo & 7) << 4;
    const bool fh = tile < 16;
    const int ncausal = fh ? ((tile * 64 + 111) >> 6) : (tile - 15);
    const int nchunks = ncausal + (fh ? 1 : 0);
    const int q0 = tile * 64 + wave * 16;            // seq position of wave's rows
    const int vcaus = fh ? q0 : (q0 - 1024 + 16);    // causal valid (keys rel. 1024)
    const long row0 = (long)bb * SEQ + q0;

    const ushort* Qp = qkv + (row0 + lo) * 2304 + head * 64 + hi * 8;
    bf16x8 qf0 = *(const bf16x8*)Qp;
    bf16x8 qf1 = *(const bf16x8*)(Qp + 32);
    f32x4 oacc[4] = {};
    float m_run = -3.0e38f, l_run = 0.f;

    const int srow = tid >> 3;  // 0..31
    const int sc8 = tid & 7;
    const ushort* Kg = qkv + ((long)bb * SEQ) * 2304 + DIM + head * 64;
    const ushort* Vg = vt + ((long)(bb * HEADS + head) * 64) * SEQ;

    auto STAGE = [&](int buf, int kbase) {
#pragma unroll
        for (int it = 0; it < 2; ++it) {
            int r = it * 32 + srow;
            int c8 = sc8 ^ (r & 7);
            GLDS16(Kg + (long)(kbase + r) * 2304 + c8 * 8,
                   (char*)Ks[buf] + it * 4096 + tid * 16);
        }
#pragma unroll
        for (int it = 0; it < 2; ++it) {
            int r = it * 32 + srow;
            int c8 = sc8 ^ (r & 7);
            GLDS16(Vg + (long)r * SEQ + kbase + c8 * 8,
                   (char*)Vs[buf] + it * 4096 + tid * 16);
        }
    };
#define KB(cc) (((cc) < ncausal) ? (1024 + (cc) * 64) : (tile * 64))

    STAGE(0, KB(0));
    for (int c = 0; c < nchunks; ++c) {
        const int cur = c & 1;
        if (c + 1 < nchunks) {
            STAGE(1 - cur, KB(c + 1));
            asm volatile("s_waitcnt vmcnt(4)" ::: "memory");
        } else {
            asm volatile("s_waitcnt vmcnt(0)" ::: "memory");
        }
        __builtin_amdgcn_s_barrier();
        __builtin_amdgcn_sched_barrier(0);
        const bool isdiag = (c >= ncausal);
        const int v = isdiag ? 16 : (vcaus - c * 64);  // wave-uniform
        if (v > 0) {
            // QK^T from Ks[cur]
            f32x4 s4[4];
#pragma unroll
            for (int n = 0; n < 4; ++n) {
                f32x4 z = {};
#pragma unroll
                for (int kk = 0; kk < 2; ++kk) {
                    const bf16x8 kf = *(const bf16x8*)((const char*)Ks[cur] +
                        ((n * 16 + lo) << 7) + ((((kk << 2) + hi) ^ (lo & 7)) << 4));
                    z = MFMA16x32(kf, kk ? qf1 : qf0, z);
                }
                s4[n] = z;
            }
            const int vv = isdiag ? 64 : min(v, 64);
            float p[4][4];
            float mx = -3.0e38f;
#pragma unroll
            for (int n = 0; n < 4; ++n)
#pragma unroll
                for (int g = 0; g < 4; ++g) {
                    bool ok = isdiag ? (n == wave) : (n * 16 + hi * 4 + g < vv);
                    float val = ok ? s4[n][g] * 0.125f : -3.0e38f;
                    p[n][g] = val;
                    mx = fmaxf(mx, val);
                }
            mx = fmaxf(mx, __shfl_xor(mx, 16, 64));
            mx = fmaxf(mx, __shfl_xor(mx, 32, 64));
            float m_new = fmaxf(m_run, mx);
            float scale = __expf(m_run - m_new);
            float psum = 0.f;
#pragma unroll
            for (int n = 0; n < 4; ++n)
#pragma unroll
                for (int g = 0; g < 4; ++g) {
                    float e = __expf(p[n][g] - m_new);  // masked -> exactly 0
                    p[n][g] = e;
                    psum += e;
                }
            psum += __shfl_xor(psum, 16, 64);
            psum += __shfl_xor(psum, 32, 64);
            l_run = l_run * scale + psum;
            m_run = m_new;
#pragma unroll
            for (int dt = 0; dt < 4; ++dt) oacc[dt] *= scale;
            // P -> bf16 pairs -> own-wave LDS (128B rows, XOR-swizzled)
#pragma unroll
            for (int n = 0; n < 4; ++n)
#pragma unroll
                for (int pr = 0; pr < 2; ++pr) {
                    uint32_t u = packbf2(p[n][pr * 2], p[n][pr * 2 + 1]);
                    *(uint32_t*)(psb + lo * 128 + ((n * 32 + hi * 8 + pr * 4) ^ swz)) = u;
                }
            bf16x8 pa0 = *(const bf16x8*)(psb + lo * 128 + ((hi * 16) ^ swz));
            bf16x8 pa1 = *(const bf16x8*)(psb + lo * 128 + ((64 + hi * 16) ^ swz));
            // PV from Vs[cur] (masked keys have P == 0 -> exact)
#pragma unroll
            for (int dt = 0; dt < 4; ++dt) {
#pragma unroll
                for (int kk = 0; kk < 2; ++kk) {
                    const bf16x8 vf = *(const bf16x8*)((const char*)Vs[cur] +
                        ((dt * 16 + lo) << 7) + ((((kk << 2) + hi) ^ (lo & 7)) << 4));
                    oacc[dt] = MFMA16x32(vf, kk ? pa1 : pa0, oacc[dt]);
                }
            }
        }
        __builtin_amdgcn_s_barrier();
        __builtin_amdgcn_sched_barrier(0);
    }
#undef KB

    float inv = 1.f / l_run;
#pragma unroll
    for (int dt = 0; dt < 4; ++dt) {
        ushort4 st;
        st.x = f2bf(oacc[dt][0] * inv);
        st.y = f2bf(oacc[dt][1] * inv);
        st.z = f2bf(oacc[dt][2] * inv);
        st.w = f2bf(oacc[dt][3] * inv);
        *(ushort4*)&o[(row0 + lo) * DIM + head * 64 + dt * 16 + hi * 4] = st;
    }
}

extern "C" void kernel_launch(void* const* d_in, const int* in_sizes, int n_in,
                              void* d_out, int out_size, void* d_ws, size_t ws_size,
                              hipStream_t stream) {
    const float* x      = (const float*)d_in[0];
    const float* cosT   = (const float*)d_in[1];
    const float* sinT   = (const float*)d_in[2];
    const float* c      = (const float*)d_in[3];
    const float* W_qkv  = (const float*)d_in[4];
    const float* W_out  = (const float*)d_in[5];
    const float* ln1_w  = (const float*)d_in[6];
    const float* ln2_w  = (const float*)d_in[7];
    const float* mlp_w1 = (const float*)d_in[8];
    const float* mlp_b1 = (const float*)d_in[9];
    const float* mlp_w2 = (const float*)d_in[10];
    const float* mlp_b2 = (const float*)d_in[11];
    const float* ada_w  = (const float*)d_in[12];
    const float* ada_b  = (const float*)d_in[13];
    float* out = (float*)d_out;

    char* ws = (char*)d_ws;
    float*  ada   = (float*)(ws + 0);
    ushort* h     = (ushort*)(ws + 65536L);
    ushort* qkv   = (ushort*)(ws + 6356992L);
    ushort* vt    = (ushort*)(ws + 25231360L);
    ushort* o     = (ushort*)(ws + 31522816L);
    float*  x1    = (float*)(ws + 37814272L);
    ushort* a1    = (ushort*)(ws + 50397184L);
    ushort* wqkvT = (ushort*)(ws + 75563008L);
    ushort* woutT = (ushort*)(ws + 79101952L);
    ushort* w1T   = (ushort*)(ws + 80281600L);
    ushort* w2T   = (ushort*)(ws + 85000192L);

    ada_kernel<<<dim3(18, 2), 256, 0, stream>>>(c, ada_w, ada_b, ada);
    convT<<<dim3(36, 12), 256, 0, stream>>>(W_qkv, wqkvT, 768, 2304);
    convT<<<dim3(12, 12), 256, 0, stream>>>(W_out, woutT, 768, 768);
    convT<<<dim3(48, 12), 256, 0, stream>>>(mlp_w1, w1T, 768, 3072);
    convT<<<dim3(12, 48), 256, 0, stream>>>(mlp_w2, w2T, 3072, 768);

    ln_mod_kernel<<<TOKENS, 256, 0, stream>>>(x, ln1_w, ada, 0, 768, h);
    gemm_bf16<0, 128><<<dim3(18, 32), 256, 0, stream>>>(h, wqkvT, qkv, TOKENS, 2304, 768,
                                                        nullptr, nullptr, nullptr, cosT, sinT);
    vtrans<<<dim3(32, 12, 2), 256, 0, stream>>>(qkv, vt);
    attn_mfma<<<dim3(32, 12, 2), 256, 0, stream>>>(qkv, vt, o);
    gemm_bf16<1, 64><<<dim3(6, 64), 256, 0, stream>>>(o, woutT, x1, TOKENS, 768, 768,
                                                      nullptr, ada + 1536, x, nullptr, nullptr);
    ln_mod_kernel<<<TOKENS, 256, 0, stream>>>(x1, ln2_w, ada, 2304, 3072, h);
    gemm_bf16<2, 128><<<dim3(24, 32), 256, 0, stream>>>(h, w1T, a1, TOKENS, DFF, 768,
                                                        mlp_b1, nullptr, nullptr, nullptr, nullptr);
    gemm_bf16<3, 64><<<dim3(6, 64), 256, 0, stream>>>(a1, w2T, out, TOKENS, 768, DFF,
                                                      mlp_b2, ada + 3840, x1, nullptr, nullptr);
}

// Round 9
// 319.458 us; speedup vs baseline: 1.1290x; 1.0252x over previous
//
#include <hip/hip_runtime.h>
#include <hip/hip_bf16.h>
#include <stdint.h>

#define DIM 768
#define SEQ 2048
#define TOKENS 4096
#define HEADS 12
#define DFF 3072
#define COND 128
#define ADA6 4608

typedef __attribute__((ext_vector_type(8))) short bf16x8;
typedef __attribute__((ext_vector_type(4))) float f32x4;

#define MFMA16x32(a, b, c) __builtin_amdgcn_mfma_f32_16x16x32_bf16(a, b, c, 0, 0, 0)
#define GLDS16(g, l)                                                                  \
    __builtin_amdgcn_global_load_lds((const __attribute__((address_space(1))) void*)(g), \
                                     (__attribute__((address_space(3))) void*)(l), 16, 0, 0)

__device__ __forceinline__ ushort f2bf(float f) {
    union { float f; uint32_t u; } v;
    v.f = f;
    uint32_t r = v.u + 0x7FFF + ((v.u >> 16) & 1);
    return (ushort)(r >> 16);
}

__device__ __forceinline__ uint32_t packbf2(float a, float b) {
    union { __hip_bfloat162 h; uint32_t u; } cv;
    cv.h = __float22bfloat162_rn(make_float2(a, b));
    return cv.u;
}

// ---------------- ada = c @ ada_w + ada_b  (2 x 4608, fp32) ----------------
__global__ void ada_kernel(const float* __restrict__ c, const float* __restrict__ ada_w,
                           const float* __restrict__ ada_b, float* __restrict__ ada) {
    int j = blockIdx.x * 256 + threadIdx.x;
    int bb = blockIdx.y;
    if (j < ADA6) {
        float acc = ada_b[j];
        for (int k = 0; k < COND; ++k)
            acc = fmaf(c[bb * COND + k], ada_w[(long)k * ADA6 + j], acc);
        ada[bb * ADA6 + j] = acc;
    }
}

// ------------- weight convert + transpose: W[K][N] f32 -> Wt[N][K] bf16 -------------
__global__ __launch_bounds__(256) void convT(const float* __restrict__ W,
                                             ushort* __restrict__ Wt, int K, int N) {
    __shared__ float t[64][65];
    int tid = threadIdx.x;
    int n0 = blockIdx.x * 64, k0 = blockIdx.y * 64;
#pragma unroll
    for (int it = 0; it < 4; ++it) {
        int idx = it * 256 + tid;
        int kr = idx >> 4, nc = (idx & 15) * 4;
        float4 v = *(const float4*)&W[(long)(k0 + kr) * N + n0 + nc];
        t[kr][nc] = v.x; t[kr][nc + 1] = v.y; t[kr][nc + 2] = v.z; t[kr][nc + 3] = v.w;
    }
    __syncthreads();
#pragma unroll
    for (int it = 0; it < 4; ++it) {
        int idx = it * 256 + tid;
        int nr = idx >> 4, kc = (idx & 15) * 4;
        ushort4 v;
        v.x = f2bf(t[kc][nr]); v.y = f2bf(t[kc + 1][nr]);
        v.z = f2bf(t[kc + 2][nr]); v.w = f2bf(t[kc + 3][nr]);
        *(ushort4*)&Wt[(long)(n0 + nr) * K + k0 + kc] = v;
    }
}

// ---------------- layernorm + adaLN modulate -> bf16 ----------------
__global__ __launch_bounds__(256) void ln_mod_kernel(const float* __restrict__ x,
                                                     const float* __restrict__ w,
                                                     const float* __restrict__ ada,
                                                     int shiftOff, int scaleOff,
                                                     ushort* __restrict__ out) {
    int token = blockIdx.x;
    int bb = token >> 11;
    int tid = threadIdx.x;
    const float* xi = x + (long)token * DIM;
    float v[3];
    float sum = 0.f, sumsq = 0.f;
#pragma unroll
    for (int t = 0; t < 3; ++t) {
        float val = xi[tid + 256 * t];
        v[t] = val;
        sum += val;
        sumsq = fmaf(val, val, sumsq);
    }
    for (int msk = 1; msk < 64; msk <<= 1) {
        sum += __shfl_xor(sum, msk, 64);
        sumsq += __shfl_xor(sumsq, msk, 64);
    }
    __shared__ float red0[4], red1[4];
    int wave = tid >> 6;
    if ((tid & 63) == 0) { red0[wave] = sum; red1[wave] = sumsq; }
    __syncthreads();
    sum = red0[0] + red0[1] + red0[2] + red0[3];
    sumsq = red1[0] + red1[1] + red1[2] + red1[3];
    float mu = sum * (1.f / DIM);
    float var = sumsq * (1.f / DIM) - mu * mu;
    float rs = rsqrtf(var + 1e-5f);
    const float* sh = ada + bb * ADA6 + shiftOff;
    const float* sc = ada + bb * ADA6 + scaleOff;
    ushort* oi = out + (long)token * DIM;
#pragma unroll
    for (int t = 0; t < 3; ++t) {
        int j = tid + 256 * t;
        oi[j] = f2bf((v[t] - mu) * rs * w[j] * (1.f + sc[j]) + sh[j]);
    }
}

// ------- bf16 MFMA GEMM, BMx128 tile, BK=64, 4 waves, 2-phase dbuf + XCD swizzle -------
// A[M][K] bf16 row-major, B = Wt[N][K] bf16 row-major.  C = A @ Wt^T.
// EPI 0: rope -> bf16 (qkv); 1: gate*acc+skip -> f32; 2: gelu(acc+bias) -> bf16;
// EPI 3: gate*(acc+bias)+skip -> f32
template <int EPI, int BM>
__global__ __launch_bounds__(256) void gemm_bf16(const ushort* __restrict__ A,
                                                 const ushort* __restrict__ B,
                                                 void* __restrict__ Cp, int M, int N, int K,
                                                 const float* __restrict__ bias,
                                                 const float* __restrict__ gate,
                                                 const float* __restrict__ skip,
                                                 const float* __restrict__ cosT,
                                                 const float* __restrict__ sinT) {
    constexpr int MR = BM / 32;  // frags per wave in M
    __shared__ ushort As[2][BM * 64];
    __shared__ ushort Bs[2][128 * 64];
    const int tid = threadIdx.x;
    const int wave = tid >> 6, lane = tid & 63;
    const int lo = lane & 15, hi = lane >> 4;
    const int wr = wave >> 1, wc = wave & 1;
    // bijective XCD swizzle: contiguous chunks of flat ids per XCD (grids %8 == 0)
    const int gx = gridDim.x;
    const int nwg = gx * gridDim.y;
    const int flat = blockIdx.y * gx + blockIdx.x;
    const int swzid = (flat & 7) * (nwg >> 3) + (flat >> 3);
    const int row0 = (swzid / gx) * BM, col0 = (swzid % gx) * 128;
    const int srow = tid >> 3;       // 0..31
    const int scol = (tid & 7) * 8;  // k elems
    f32x4 acc[MR][4] = {};
    const long astep = (long)32 * K;
    const ushort* Ag = A + (long)(row0 + srow) * K + scol;
    const ushort* Bg = B + (long)(col0 + srow) * K + scol;

    auto STAGE = [&](int buf, int kt) {
        const int k0 = kt * 64;
#pragma unroll
        for (int t = 0; t < MR; ++t)
            GLDS16(Ag + t * astep + k0, (char*)As[buf] + (t * 256 + tid) * 16);
#pragma unroll
        for (int t = 0; t < 4; ++t)
            GLDS16(Bg + t * astep + k0, (char*)Bs[buf] + (t * 256 + tid) * 16);
    };

    const int nkt = K >> 6;
    STAGE(0, 0);
    for (int kt = 0; kt < nkt; ++kt) {
        const int cur = kt & 1;
        if (kt + 1 < nkt) {
            STAGE(1 - cur, kt + 1);
            // wait for stage kt only; stage kt+1 stays in flight across the barrier
            if constexpr (BM == 128)
                asm volatile("s_waitcnt vmcnt(8)" ::: "memory");
            else
                asm volatile("s_waitcnt vmcnt(6)" ::: "memory");
        } else {
            asm volatile("s_waitcnt vmcnt(0)" ::: "memory");
        }
        __builtin_amdgcn_s_barrier();
        __builtin_amdgcn_sched_barrier(0);
#pragma unroll
        for (int kk = 0; kk < 2; ++kk) {
            bf16x8 af[MR], bfr[4];
#pragma unroll
            for (int m = 0; m < MR; ++m)
                af[m] = *(const bf16x8*)&As[cur][(wr * (BM / 2) + m * 16 + lo) * 64 + kk * 32 + hi * 8];
#pragma unroll
            for (int n = 0; n < 4; ++n)
                bfr[n] = *(const bf16x8*)&Bs[cur][(wc * 64 + n * 16 + lo) * 64 + kk * 32 + hi * 8];
#pragma unroll
            for (int m = 0; m < MR; ++m)
#pragma unroll
                for (int n = 0; n < 4; ++n)
                    acc[m][n] = MFMA16x32(af[m], bfr[n], acc[m][n]);
        }
        __builtin_amdgcn_s_barrier();  // protect buf 1-cur from next iteration's STAGE
    }
    // epilogue: lane holds C[row0+wr*(BM/2)+m*16+hi*4+reg][col0+wc*64+n*16+lo]
    if (EPI == 0) {
        ushort* C = (ushort*)Cp;
#pragma unroll
        for (int m = 0; m < MR; ++m)
#pragma unroll
            for (int reg = 0; reg < 4; ++reg) {
                int r = row0 + wr * (BM / 2) + m * 16 + hi * 4 + reg;
                int pos = r & 1023;
                const float* cb = cosT + pos * 64;
                const float* sb = sinT + pos * 64;
                long rb = (long)r * N + col0 + wc * 64;
#pragma unroll
                for (int pr = 0; pr < 2; ++pr) {
                    int i = pr * 16 + lo;
                    float v0 = acc[m][pr][reg], v1 = acc[m][pr + 2][reg];
                    float c0 = cb[i], s0 = sb[i], c1 = cb[i + 32], s1 = sb[i + 32];
                    C[rb + i] = f2bf(v0 * c0 - v1 * s0);
                    C[rb + i + 32] = f2bf(v1 * c1 + v0 * s1);
                }
            }
    } else if (EPI == 1) {
        float* C = (float*)Cp;
#pragma unroll
        for (int m = 0; m < MR; ++m)
#pragma unroll
            for (int reg = 0; reg < 4; ++reg) {
                int r = row0 + wr * (BM / 2) + m * 16 + hi * 4 + reg;
                int bbi = r >> 11;
#pragma unroll
                for (int n = 0; n < 4; ++n) {
                    int c = col0 + wc * 64 + n * 16 + lo;
                    C[(long)r * N + c] =
                        gate[bbi * ADA6 + c] * acc[m][n][reg] + skip[(long)r * DIM + c];
                }
            }
    } else if (EPI == 2) {
        ushort* C = (ushort*)Cp;
#pragma unroll
        for (int m = 0; m < MR; ++m)
#pragma unroll
            for (int reg = 0; reg < 4; ++reg) {
                int r = row0 + wr * (BM / 2) + m * 16 + hi * 4 + reg;
#pragma unroll
                for (int n = 0; n < 4; ++n) {
                    int c = col0 + wc * 64 + n * 16 + lo;
                    float v = acc[m][n][reg] + bias[c];
                    float g = v / (1.f + __expf(-1.5957691216f * (v + 0.044715f * v * v * v)));
                    C[(long)r * N + c] = f2bf(g);
                }
            }
    } else {
        float* C = (float*)Cp;
#pragma unroll
        for (int m = 0; m < MR; ++m)
#pragma unroll
            for (int reg = 0; reg < 4; ++reg) {
                int r = row0 + wr * (BM / 2) + m * 16 + hi * 4 + reg;
                int bbi = r >> 11;
#pragma unroll
                for (int n = 0; n < 4; ++n) {
                    int c = col0 + wc * 64 + n * 16 + lo;
                    C[(long)r * N + c] = gate[bbi * ADA6 + c] * (acc[m][n][reg] + bias[c]) +
                                         skip[(long)r * DIM + c];
                }
            }
    }
}

// ------------- V transpose: qkv[tok][1536+h*64+d] -> vt[(bb*12+h)*64+d][tok] -------------
__global__ __launch_bounds__(256) void vtrans(const ushort* __restrict__ qkv,
                                              ushort* __restrict__ vt) {
    __shared__ ushort t[64][65];
    int tid = threadIdx.x;
    int tb = blockIdx.x;
    int head = blockIdx.y;
    int bb = blockIdx.z;
#pragma unroll
    for (int it = 0; it < 4; ++it) {
        int idx = it * 256 + tid;
        int tok = idx >> 4, d4 = (idx & 15) * 4;
        const ushort* p = qkv + ((long)bb * SEQ + tb * 64 + tok) * 2304 + 1536 + head * 64 + d4;
        ushort4 v = *(const ushort4*)p;
        t[tok][d4] = v.x; t[tok][d4 + 1] = v.y; t[tok][d4 + 2] = v.z; t[tok][d4 + 3] = v.w;
    }
    __syncthreads();
#pragma unroll
    for (int it = 0; it < 4; ++it) {
        int idx = it * 256 + tid;
        int d = idx >> 4, t4 = (idx & 15) * 4;
        ushort4 v;
        v.x = t[t4][d]; v.y = t[t4 + 1][d]; v.z = t[t4 + 2][d]; v.w = t[t4 + 3][d];
        *(ushort4*)&vt[((long)(bb * HEADS + head) * 64 + d) * SEQ + tb * 64 + t4] = v;
    }
}

// ---------------- MFMA flash attention: shared-KV LDS, 2-phase pipeline ----------------
// grid (32 tiles, 12 heads, 2 bb), 256 thr. Block = 64 q rows (4 qblocks); wave w owns
// qblock tile*4+w. All waves share each 64-key chunk, staged into double-buffered LDS
// via global_load_lds (linear dest, inverse-swizzled source, swizzled reads).
__global__ __launch_bounds__(256) void attn_mfma(const ushort* __restrict__ qkv,
                                                 const ushort* __restrict__ vt,
                                                 ushort* __restrict__ o) {
    __shared__ ushort Ks[2][4096];  // [64 key][64 d], rows XOR-swizzled by (row&7)
    __shared__ ushort Vs[2][4096];  // [64 d][64 key], same swizzle
    __shared__ char ps[4][2048];    // per-wave P: 16 q rows x 128 B
    const int tid = threadIdx.x;
    const int wave = tid >> 6, lane = tid & 63;
    const int lo = lane & 15, hi = lane >> 4;
    const int bx = blockIdx.x;
    const int tile = (bx & 1) ? (31 - (bx >> 1)) : (15 - (bx >> 1));  // heavy first
    const int head = blockIdx.y;
    const int bb = blockIdx.z;
    char* psb = ps[wave];
    const int swz = (lo & 7) << 4;
    const bool fh = tile < 16;
    const int ncausal = fh ? ((tile * 64 + 111) >> 6) : (tile - 15);
    const int nchunks = ncausal + (fh ? 1 : 0);
    const int q0 = tile * 64 + wave * 16;            // seq position of wave's rows
    const int vcaus = fh ? q0 : (q0 - 1024 + 16);    // causal valid (keys rel. 1024)
    const long row0 = (long)bb * SEQ + q0;

    const ushort* Qp = qkv + (row0 + lo) * 2304 + head * 64 + hi * 8;
    bf16x8 qf0 = *(const bf16x8*)Qp;
    bf16x8 qf1 = *(const bf16x8*)(Qp + 32);
    f32x4 oacc[4] = {};
    float m_run = -3.0e38f, l_run = 0.f;

    const int srow = tid >> 3;  // 0..31
    const int sc8 = tid & 7;
    const ushort* Kg = qkv + ((long)bb * SEQ) * 2304 + DIM + head * 64;
    const ushort* Vg = vt + ((long)(bb * HEADS + head) * 64) * SEQ;

    auto STAGE = [&](int buf, int kbase) {
#pragma unroll
        for (int it = 0; it < 2; ++it) {
            int r = it * 32 + srow;
            int c8 = sc8 ^ (r & 7);
            GLDS16(Kg + (long)(kbase + r) * 2304 + c8 * 8,
                   (char*)Ks[buf] + it * 4096 + tid * 16);
        }
#pragma unroll
        for (int it = 0; it < 2; ++it) {
            int r = it * 32 + srow;
            int c8 = sc8 ^ (r & 7);
            GLDS16(Vg + (long)r * SEQ + kbase + c8 * 8,
                   (char*)Vs[buf] + it * 4096 + tid * 16);
        }
    };
#define KB(cc) (((cc) < ncausal) ? (1024 + (cc) * 64) : (tile * 64))

    STAGE(0, KB(0));
    for (int c = 0; c < nchunks; ++c) {
        const int cur = c & 1;
        if (c + 1 < nchunks) {
            STAGE(1 - cur, KB(c + 1));
            asm volatile("s_waitcnt vmcnt(4)" ::: "memory");
        } else {
            asm volatile("s_waitcnt vmcnt(0)" ::: "memory");
        }
        __builtin_amdgcn_s_barrier();
        __builtin_amdgcn_sched_barrier(0);
        const bool isdiag = (c >= ncausal);
        const int v = isdiag ? 16 : (vcaus - c * 64);  // wave-uniform
        if (v > 0) {
            // QK^T from Ks[cur]
            f32x4 s4[4];
#pragma unroll
            for (int n = 0; n < 4; ++n) {
                f32x4 z = {};
#pragma unroll
                for (int kk = 0; kk < 2; ++kk) {
                    const bf16x8 kf = *(const bf16x8*)((const char*)Ks[cur] +
                        ((n * 16 + lo) << 7) + ((((kk << 2) + hi) ^ (lo & 7)) << 4));
                    z = MFMA16x32(kf, kk ? qf1 : qf0, z);
                }
                s4[n] = z;
            }
            const int vv = isdiag ? 64 : min(v, 64);
            float p[4][4];
            float mx = -3.0e38f;
#pragma unroll
            for (int n = 0; n < 4; ++n)
#pragma unroll
                for (int g = 0; g < 4; ++g) {
                    bool ok = isdiag ? (n == wave) : (n * 16 + hi * 4 + g < vv);
                    float val = ok ? s4[n][g] * 0.125f : -3.0e38f;
                    p[n][g] = val;
                    mx = fmaxf(mx, val);
                }
            mx = fmaxf(mx, __shfl_xor(mx, 16, 64));
            mx = fmaxf(mx, __shfl_xor(mx, 32, 64));
            float m_new = fmaxf(m_run, mx);
            float scale = __expf(m_run - m_new);
            float psum = 0.f;
#pragma unroll
            for (int n = 0; n < 4; ++n)
#pragma unroll
                for (int g = 0; g < 4; ++g) {
                    float e = __expf(p[n][g] - m_new);  // masked -> exactly 0
                    p[n][g] = e;
                    psum += e;
                }
            psum += __shfl_xor(psum, 16, 64);
            psum += __shfl_xor(psum, 32, 64);
            l_run = l_run * scale + psum;
            m_run = m_new;
#pragma unroll
            for (int dt = 0; dt < 4; ++dt) oacc[dt] *= scale;
            // P -> bf16 pairs -> own-wave LDS (128B rows, XOR-swizzled)
#pragma unroll
            for (int n = 0; n < 4; ++n)
#pragma unroll
                for (int pr = 0; pr < 2; ++pr) {
                    uint32_t u = packbf2(p[n][pr * 2], p[n][pr * 2 + 1]);
                    *(uint32_t*)(psb + lo * 128 + ((n * 32 + hi * 8 + pr * 4) ^ swz)) = u;
                }
            bf16x8 pa0 = *(const bf16x8*)(psb + lo * 128 + ((hi * 16) ^ swz));
            bf16x8 pa1 = *(const bf16x8*)(psb + lo * 128 + ((64 + hi * 16) ^ swz));
            // PV from Vs[cur] (masked keys have P == 0 -> exact)
#pragma unroll
            for (int dt = 0; dt < 4; ++dt) {
#pragma unroll
                for (int kk = 0; kk < 2; ++kk) {
                    const bf16x8 vf = *(const bf16x8*)((const char*)Vs[cur] +
                        ((dt * 16 + lo) << 7) + ((((kk << 2) + hi) ^ (lo & 7)) << 4));
                    oacc[dt] = MFMA16x32(vf, kk ? pa1 : pa0, oacc[dt]);
                }
            }
        }
        __builtin_amdgcn_s_barrier();
        __builtin_amdgcn_sched_barrier(0);
    }
#undef KB

    float inv = 1.f / l_run;
#pragma unroll
    for (int dt = 0; dt < 4; ++dt) {
        ushort4 st;
        st.x = f2bf(oacc[dt][0] * inv);
        st.y = f2bf(oacc[dt][1] * inv);
        st.z = f2bf(oacc[dt][2] * inv);
        st.w = f2bf(oacc[dt][3] * inv);
        *(ushort4*)&o[(row0 + lo) * DIM + head * 64 + dt * 16 + hi * 4] = st;
    }
}

extern "C" void kernel_launch(void* const* d_in, const int* in_sizes, int n_in,
                              void* d_out, int out_size, void* d_ws, size_t ws_size,
                              hipStream_t stream) {
    const float* x      = (const float*)d_in[0];
    const float* cosT   = (const float*)d_in[1];
    const float* sinT   = (const float*)d_in[2];
    const float* c      = (const float*)d_in[3];
    const float* W_qkv  = (const float*)d_in[4];
    const float* W_out  = (const float*)d_in[5];
    const float* ln1_w  = (const float*)d_in[6];
    const float* ln2_w  = (const float*)d_in[7];
    const float* mlp_w1 = (const float*)d_in[8];
    const float* mlp_b1 = (const float*)d_in[9];
    const float* mlp_w2 = (const float*)d_in[10];
    const float* mlp_b2 = (const float*)d_in[11];
    const float* ada_w  = (const float*)d_in[12];
    const float* ada_b  = (const float*)d_in[13];
    float* out = (float*)d_out;

    char* ws = (char*)d_ws;
    float*  ada   = (float*)(ws + 0);
    ushort* h     = (ushort*)(ws + 65536L);
    ushort* qkv   = (ushort*)(ws + 6356992L);
    ushort* vt    = (ushort*)(ws + 25231360L);
    ushort* o     = (ushort*)(ws + 31522816L);
    float*  x1    = (float*)(ws + 37814272L);
    ushort* a1    = (ushort*)(ws + 50397184L);
    ushort* wqkvT = (ushort*)(ws + 75563008L);
    ushort* woutT = (ushort*)(ws + 79101952L);
    ushort* w1T   = (ushort*)(ws + 80281600L);
    ushort* w2T   = (ushort*)(ws + 85000192L);

    ada_kernel<<<dim3(18, 2), 256, 0, stream>>>(c, ada_w, ada_b, ada);
    convT<<<dim3(36, 12), 256, 0, stream>>>(W_qkv, wqkvT, 768, 2304);
    convT<<<dim3(12, 12), 256, 0, stream>>>(W_out, woutT, 768, 768);
    convT<<<dim3(48, 12), 256, 0, stream>>>(mlp_w1, w1T, 768, 3072);
    convT<<<dim3(12, 48), 256, 0, stream>>>(mlp_w2, w2T, 3072, 768);

    ln_mod_kernel<<<TOKENS, 256, 0, stream>>>(x, ln1_w, ada, 0, 768, h);
    gemm_bf16<0, 128><<<dim3(18, 32), 256, 0, stream>>>(h, wqkvT, qkv, TOKENS, 2304, 768,
                                                        nullptr, nullptr, nullptr, cosT, sinT);
    vtrans<<<dim3(32, 12, 2), 256, 0, stream>>>(qkv, vt);
    attn_mfma<<<dim3(32, 12, 2), 256, 0, stream>>>(qkv, vt, o);
    gemm_bf16<1, 64><<<dim3(6, 64), 256, 0, stream>>>(o, woutT, x1, TOKENS, 768, 768,
                                                      nullptr, ada + 1536, x, nullptr, nullptr);
    ln_mod_kernel<<<TOKENS, 256, 0, stream>>>(x1, ln2_w, ada, 2304, 3072, h);
    gemm_bf16<2, 128><<<dim3(24, 32), 256, 0, stream>>>(h, w1T, a1, TOKENS, DFF, 768,
                                                        mlp_b1, nullptr, nullptr, nullptr, nullptr);
    gemm_bf16<3, 64><<<dim3(6, 64), 256, 0, stream>>>(a1, w2T, out, TOKENS, 768, DFF,
                                                      mlp_b2, ada + 3840, x1, nullptr, nullptr);
}

// Round 11
// 293.368 us; speedup vs baseline: 1.2295x; 1.0889x over previous
//
#include <hip/hip_runtime.h>
#include <hip/hip_bf16.h>
#include <stdint.h>

#define DIM 768
#define SEQ 2048
#define TOKENS 4096
#define HEADS 12
#define DFF 3072
#define COND 128
#define ADA6 4608

typedef __attribute__((ext_vector_type(8))) short bf16x8;
typedef __attribute__((ext_vector_type(4))) float f32x4;

#define MFMA16x32(a, b, c) __builtin_amdgcn_mfma_f32_16x16x32_bf16(a, b, c, 0, 0, 0)
#define GLDS16(g, l)                                                                  \
    __builtin_amdgcn_global_load_lds((const __attribute__((address_space(1))) void*)(g), \
                                     (__attribute__((address_space(3))) void*)(l), 16, 0, 0)

__device__ __forceinline__ ushort f2bf(float f) {
    union { float f; uint32_t u; } v;
    v.f = f;
    uint32_t r = v.u + 0x7FFF + ((v.u >> 16) & 1);
    return (ushort)(r >> 16);
}

__device__ __forceinline__ uint32_t packbf2(float a, float b) {
    union { __hip_bfloat162 h; uint32_t u; } cv;
    cv.h = __float22bfloat162_rn(make_float2(a, b));
    return cv.u;
}

// ---------------- ada = c @ ada_w + ada_b  (2 x 4608, fp32) ----------------
__global__ void ada_kernel(const float* __restrict__ c, const float* __restrict__ ada_w,
                           const float* __restrict__ ada_b, float* __restrict__ ada) {
    int j = blockIdx.x * 256 + threadIdx.x;
    int bb = blockIdx.y;
    if (j < ADA6) {
        float acc = ada_b[j];
        for (int k = 0; k < COND; ++k)
            acc = fmaf(c[bb * COND + k], ada_w[(long)k * ADA6 + j], acc);
        ada[bb * ADA6 + j] = acc;
    }
}

// ------------- weight convert + transpose: W[K][N] f32 -> Wt[N][K] bf16 -------------
__global__ __launch_bounds__(256) void convT(const float* __restrict__ W,
                                             ushort* __restrict__ Wt, int K, int N) {
    __shared__ float t[64][65];
    int tid = threadIdx.x;
    int n0 = blockIdx.x * 64, k0 = blockIdx.y * 64;
#pragma unroll
    for (int it = 0; it < 4; ++it) {
        int idx = it * 256 + tid;
        int kr = idx >> 4, nc = (idx & 15) * 4;
        float4 v = *(const float4*)&W[(long)(k0 + kr) * N + n0 + nc];
        t[kr][nc] = v.x; t[kr][nc + 1] = v.y; t[kr][nc + 2] = v.z; t[kr][nc + 3] = v.w;
    }
    __syncthreads();
#pragma unroll
    for (int it = 0; it < 4; ++it) {
        int idx = it * 256 + tid;
        int nr = idx >> 4, kc = (idx & 15) * 4;
        ushort4 v;
        v.x = f2bf(t[kc][nr]); v.y = f2bf(t[kc + 1][nr]);
        v.z = f2bf(t[kc + 2][nr]); v.w = f2bf(t[kc + 3][nr]);
        *(ushort4*)&Wt[(long)(n0 + nr) * K + k0 + kc] = v;
    }
}

// ---------------- layernorm + adaLN modulate -> bf16 ----------------
__global__ __launch_bounds__(256) void ln_mod_kernel(const float* __restrict__ x,
                                                     const float* __restrict__ w,
                                                     const float* __restrict__ ada,
                                                     int shiftOff, int scaleOff,
                                                     ushort* __restrict__ out) {
    int token = blockIdx.x;
    int bb = token >> 11;
    int tid = threadIdx.x;
    const float* xi = x + (long)token * DIM;
    float v[3];
    float sum = 0.f, sumsq = 0.f;
#pragma unroll
    for (int t = 0; t < 3; ++t) {
        float val = xi[tid + 256 * t];
        v[t] = val;
        sum += val;
        sumsq = fmaf(val, val, sumsq);
    }
    for (int msk = 1; msk < 64; msk <<= 1) {
        sum += __shfl_xor(sum, msk, 64);
        sumsq += __shfl_xor(sumsq, msk, 64);
    }
    __shared__ float red0[4], red1[4];
    int wave = tid >> 6;
    if ((tid & 63) == 0) { red0[wave] = sum; red1[wave] = sumsq; }
    __syncthreads();
    sum = red0[0] + red0[1] + red0[2] + red0[3];
    sumsq = red1[0] + red1[1] + red1[2] + red1[3];
    float mu = sum * (1.f / DIM);
    float var = sumsq * (1.f / DIM) - mu * mu;
    float rs = rsqrtf(var + 1e-5f);
    const float* sh = ada + bb * ADA6 + shiftOff;
    const float* sc = ada + bb * ADA6 + scaleOff;
    ushort* oi = out + (long)token * DIM;
#pragma unroll
    for (int t = 0; t < 3; ++t) {
        int j = tid + 256 * t;
        oi[j] = f2bf((v[t] - mu) * rs * w[j] * (1.f + sc[j]) + sh[j]);
    }
}

// -- bf16 MFMA GEMM, BMx128 tile, BK=64, 2-phase dbuf, T2 LDS swizzle, XCD swizzle --
// A[M][K*SPLITK] bf16 row-major, B = Wt[N][K*SPLITK] bf16 row-major.  C = A @ Wt^T.
// blockIdx.z = K segment (SPLITK>1). K arg = per-segment K length.
// EPI 0: rope->bf16; 1: gate*acc+skip->f32; 2: gelu(acc+bias)->bf16;
// EPI 3: gate*(acc+bias)+skip->f32; 4: raw fp32 partial (split-K)
template <int EPI, int BM, int SPLITK = 1>
__global__ __launch_bounds__(256) void gemm_bf16(const ushort* __restrict__ A,
                                                 const ushort* __restrict__ B,
                                                 void* __restrict__ Cp, int M, int N, int K,
                                                 const float* __restrict__ bias,
                                                 const float* __restrict__ gate,
                                                 const float* __restrict__ skip,
                                                 const float* __restrict__ cosT,
                                                 const float* __restrict__ sinT) {
    constexpr int MR = BM / 32;  // frags per wave in M
    __shared__ ushort As[2][BM * 64];
    __shared__ ushort Bs[2][128 * 64];
    const int tid = threadIdx.x;
    const int wave = tid >> 6, lane = tid & 63;
    const int lo = lane & 15, hi = lane >> 4;
    const int wr = wave >> 1, wc = wave & 1;
    // bijective XCD swizzle over (x,y); z is the K segment
    const int gx = gridDim.x;
    const int nwg = gx * gridDim.y;
    const int flat = blockIdx.y * gx + blockIdx.x;
    const int swzid = (flat & 7) * (nwg >> 3) + (flat >> 3);
    const int row0 = (swzid / gx) * BM, col0 = (swzid % gx) * 128;
    const int srow = tid >> 3;                          // 0..31
    const int xscol = (((tid & 7) ^ (srow & 7)) * 8);   // T2: inverse-swizzled source col
    f32x4 acc[MR][4] = {};
    const long lda = (long)K * SPLITK;
    const long koff = (long)blockIdx.z * K;
    const long astep = 32 * lda;
    const ushort* Ag = A + (long)(row0 + srow) * lda + koff + xscol;
    const ushort* Bg = B + (long)(col0 + srow) * lda + koff + xscol;

    auto STAGE = [&](int buf, int kt) {
        const int k0 = kt * 64;
#pragma unroll
        for (int t = 0; t < MR; ++t)
            GLDS16(Ag + t * astep + k0, (char*)As[buf] + (t * 256 + tid) * 16);
#pragma unroll
        for (int t = 0; t < 4; ++t)
            GLDS16(Bg + t * astep + k0, (char*)Bs[buf] + (t * 256 + tid) * 16);
    };

    const int nkt = K >> 6;
    STAGE(0, 0);
    for (int kt = 0; kt < nkt; ++kt) {
        const int cur = kt & 1;
        if (kt + 1 < nkt) {
            STAGE(1 - cur, kt + 1);
            if constexpr (BM == 128)
                asm volatile("s_waitcnt vmcnt(8)" ::: "memory");
            else
                asm volatile("s_waitcnt vmcnt(6)" ::: "memory");
        } else {
            asm volatile("s_waitcnt vmcnt(0)" ::: "memory");
        }
        __builtin_amdgcn_s_barrier();
        __builtin_amdgcn_sched_barrier(0);
#pragma unroll
        for (int kk = 0; kk < 2; ++kk) {
            bf16x8 af[MR], bfr[4];
#pragma unroll
            for (int m = 0; m < MR; ++m) {
                const int R = wr * (BM / 2) + m * 16 + lo;  // R&7 == lo&7
                af[m] = *(const bf16x8*)((const char*)As[cur] + R * 128 +
                                         ((((kk << 2) + hi) ^ (lo & 7)) << 4));
            }
#pragma unroll
            for (int n = 0; n < 4; ++n) {
                const int R = wc * 64 + n * 16 + lo;
                bfr[n] = *(const bf16x8*)((const char*)Bs[cur] + R * 128 +
                                          ((((kk << 2) + hi) ^ (lo & 7)) << 4));
            }
#pragma unroll
            for (int m = 0; m < MR; ++m)
#pragma unroll
                for (int n = 0; n < 4; ++n)
                    acc[m][n] = MFMA16x32(af[m], bfr[n], acc[m][n]);
        }
        __builtin_amdgcn_s_barrier();  // protect buf 1-cur from next STAGE
    }
    // epilogue: lane holds C[row0+wr*(BM/2)+m*16+hi*4+reg][col0+wc*64+n*16+lo]
    if (EPI == 0) {
        ushort* C = (ushort*)Cp;
#pragma unroll
        for (int m = 0; m < MR; ++m)
#pragma unroll
            for (int reg = 0; reg < 4; ++reg) {
                int r = row0 + wr * (BM / 2) + m * 16 + hi * 4 + reg;
                int pos = r & 1023;
                const float* cb = cosT + pos * 64;
                const float* sb = sinT + pos * 64;
                long rb = (long)r * N + col0 + wc * 64;
#pragma unroll
                for (int pr = 0; pr < 2; ++pr) {
                    int i = pr * 16 + lo;
                    float v0 = acc[m][pr][reg], v1 = acc[m][pr + 2][reg];
                    float c0 = cb[i], s0 = sb[i], c1 = cb[i + 32], s1 = sb[i + 32];
                    C[rb + i] = f2bf(v0 * c0 - v1 * s0);
                    C[rb + i + 32] = f2bf(v1 * c1 + v0 * s1);
                }
            }
    } else if (EPI == 1) {
        float* C = (float*)Cp;
#pragma unroll
        for (int m = 0; m < MR; ++m)
#pragma unroll
            for (int reg = 0; reg < 4; ++reg) {
                int r = row0 + wr * (BM / 2) + m * 16 + hi * 4 + reg;
                int bbi = r >> 11;
#pragma unroll
                for (int n = 0; n < 4; ++n) {
                    int c = col0 + wc * 64 + n * 16 + lo;
                    C[(long)r * N + c] =
                        gate[bbi * ADA6 + c] * acc[m][n][reg] + skip[(long)r * DIM + c];
                }
            }
    } else if (EPI == 2) {
        ushort* C = (ushort*)Cp;
#pragma unroll
        for (int m = 0; m < MR; ++m)
#pragma unroll
            for (int reg = 0; reg < 4; ++reg) {
                int r = row0 + wr * (BM / 2) + m * 16 + hi * 4 + reg;
#pragma unroll
                for (int n = 0; n < 4; ++n) {
                    int c = col0 + wc * 64 + n * 16 + lo;
                    float v = acc[m][n][reg] + bias[c];
                    float g = v / (1.f + __expf(-1.5957691216f * (v + 0.044715f * v * v * v)));
                    C[(long)r * N + c] = f2bf(g);
                }
            }
    } else if (EPI == 3) {
        float* C = (float*)Cp;
#pragma unroll
        for (int m = 0; m < MR; ++m)
#pragma unroll
            for (int reg = 0; reg < 4; ++reg) {
                int r = row0 + wr * (BM / 2) + m * 16 + hi * 4 + reg;
                int bbi = r >> 11;
#pragma unroll
                for (int n = 0; n < 4; ++n) {
                    int c = col0 + wc * 64 + n * 16 + lo;
                    C[(long)r * N + c] = gate[bbi * ADA6 + c] * (acc[m][n][reg] + bias[c]) +
                                         skip[(long)r * DIM + c];
                }
            }
    } else {  // EPI 4: raw fp32 partial for split-K
        float* C = (float*)Cp + (long)blockIdx.z * M * N;
#pragma unroll
        for (int m = 0; m < MR; ++m)
#pragma unroll
            for (int reg = 0; reg < 4; ++reg) {
                int r = row0 + wr * (BM / 2) + m * 16 + hi * 4 + reg;
#pragma unroll
                for (int n = 0; n < 4; ++n) {
                    int c = col0 + wc * 64 + n * 16 + lo;
                    C[(long)r * N + c] = acc[m][n][reg];
                }
            }
    }
}

// ---- split-K reduce + mlp2 epilogue: out = gate_mlp*(p0+p1+bias)+skip ----
__global__ __launch_bounds__(256) void splitk_red(const float* __restrict__ part,
                                                  const float* __restrict__ bias,
                                                  const float* __restrict__ ada,
                                                  const float* __restrict__ skip,
                                                  float* __restrict__ C) {
    long i = ((long)blockIdx.x * 256 + threadIdx.x) * 4;  // over 4096*768 elems
    int col = (int)(i % DIM);
    int row = (int)(i / DIM);
    int bb = row >> 11;
    float4 a = *(const float4*)&part[i];
    float4 b = *(const float4*)&part[(long)TOKENS * DIM + i];
    float4 bi = *(const float4*)&bias[col];
    float4 g = *(const float4*)&ada[bb * ADA6 + 3840 + col];
    float4 s = *(const float4*)&skip[i];
    float4 r;
    r.x = g.x * (a.x + b.x + bi.x) + s.x;
    r.y = g.y * (a.y + b.y + bi.y) + s.y;
    r.z = g.z * (a.z + b.z + bi.z) + s.z;
    r.w = g.w * (a.w + b.w + bi.w) + s.w;
    *(float4*)&C[i] = r;
}

// ------------- V transpose: qkv[tok][1536+h*64+d] -> vt[(bb*12+h)*64+d][tok] -------------
__global__ __launch_bounds__(256) void vtrans(const ushort* __restrict__ qkv,
                                              ushort* __restrict__ vt) {
    __shared__ ushort t[64][65];
    int tid = threadIdx.x;
    int tb = blockIdx.x;
    int head = blockIdx.y;
    int bb = blockIdx.z;
#pragma unroll
    for (int it = 0; it < 4; ++it) {
        int idx = it * 256 + tid;
        int tok = idx >> 4, d4 = (idx & 15) * 4;
        const ushort* p = qkv + ((long)bb * SEQ + tb * 64 + tok) * 2304 + 1536 + head * 64 + d4;
        ushort4 v = *(const ushort4*)p;
        t[tok][d4] = v.x; t[tok][d4 + 1] = v.y; t[tok][d4 + 2] = v.z; t[tok][d4 + 3] = v.w;
    }
    __syncthreads();
#pragma unroll
    for (int it = 0; it < 4; ++it) {
        int idx = it * 256 + tid;
        int d = idx >> 4, t4 = (idx & 15) * 4;
        ushort4 v;
        v.x = t[t4][d]; v.y = t[t4 + 1][d]; v.z = t[t4 + 2][d]; v.w = t[t4 + 3][d];
        *(ushort4*)&vt[((long)(bb * HEADS + head) * 64 + d) * SEQ + tb * 64 + t4] = v;
    }
}

// ---------------- MFMA flash attention: shared-KV LDS, 2-phase pipeline ----------------
__global__ __launch_bounds__(256) void attn_mfma(const ushort* __restrict__ qkv,
                                                 const ushort* __restrict__ vt,
                                                 ushort* __restrict__ o) {
    __shared__ ushort Ks[2][4096];  // [64 key][64 d], rows XOR-swizzled by (row&7)
    __shared__ ushort Vs[2][4096];  // [64 d][64 key], same swizzle
    __shared__ char ps[4][2048];    // per-wave P: 16 q rows x 128 B
    const int tid = threadIdx.x;
    const int wave = tid >> 6, lane = tid & 63;
    const int lo = lane & 15, hi = lane >> 4;
    const int bx = blockIdx.x;
    const int tile = (bx & 1) ? (31 - (bx >> 1)) : (15 - (bx >> 1));  // heavy first
    const int head = blockIdx.y;
    const int bb = blockIdx.z;
    char* psb = ps[wave];
    const int swz = (lo & 7) << 4;
    const bool fh = tile < 16;
    const int ncausal = fh ? ((tile * 64 + 111) >> 6) : (tile - 15);
    const int nchunks = ncausal + (fh ? 1 : 0);
    const int q0 = tile * 64 + wave * 16;
    const int vcaus = fh ? q0 : (q0 - 1024 + 16);
    const long row0 = (long)bb * SEQ + q0;

    const ushort* Qp = qkv + (row0 + lo) * 2304 + head * 64 + hi * 8;
    bf16x8 qf0 = *(const bf16x8*)Qp;
    bf16x8 qf1 = *(const bf16x8*)(Qp + 32);
    f32x4 oacc[4] = {};
    float m_run = -3.0e38f, l_run = 0.f;

    const int srow = tid >> 3;
    const int sc8 = tid & 7;
    const ushort* Kg = qkv + ((long)bb * SEQ) * 2304 + DIM + head * 64;
    const ushort* Vg = vt + ((long)(bb * HEADS + head) * 64) * SEQ;

    auto STAGE = [&](int buf, int kbase) {
#pragma unroll
        for (int it = 0; it < 2; ++it) {
            int r = it * 32 + srow;
            int c8 = sc8 ^ (r & 7);
            GLDS16(Kg + (long)(kbase + r) * 2304 + c8 * 8,
                   (char*)Ks[buf] + it * 4096 + tid * 16);
        }
#pragma unroll
        for (int it = 0; it < 2; ++it) {
            int r = it * 32 + srow;
            int c8 = sc8 ^ (r & 7);
            GLDS16(Vg + (long)r * SEQ + kbase + c8 * 8,
                   (char*)Vs[buf] + it * 4096 + tid * 16);
        }
    };
#define KB(cc) (((cc) < ncausal) ? (1024 + (cc) * 64) : (tile * 64))

    STAGE(0, KB(0));
    for (int c = 0; c < nchunks; ++c) {
        const int cur = c & 1;
        if (c + 1 < nchunks) {
            STAGE(1 - cur, KB(c + 1));
            asm volatile("s_waitcnt vmcnt(4)" ::: "memory");
        } else {
            asm volatile("s_waitcnt vmcnt(0)" ::: "memory");
        }
        __builtin_amdgcn_s_barrier();
        __builtin_amdgcn_sched_barrier(0);
        const bool isdiag = (c >= ncausal);
        const int v = isdiag ? 16 : (vcaus - c * 64);  // wave-uniform
        if (v > 0) {
            f32x4 s4[4];
#pragma unroll
            for (int n = 0; n < 4; ++n) {
                f32x4 z = {};
#pragma unroll
                for (int kk = 0; kk < 2; ++kk) {
                    const bf16x8 kf = *(const bf16x8*)((const char*)Ks[cur] +
                        ((n * 16 + lo) << 7) + ((((kk << 2) + hi) ^ (lo & 7)) << 4));
                    z = MFMA16x32(kf, kk ? qf1 : qf0, z);
                }
                s4[n] = z;
            }
            const int vv = isdiag ? 64 : min(v, 64);
            float p[4][4];
            float mx = -3.0e38f;
#pragma unroll
            for (int n = 0; n < 4; ++n)
#pragma unroll
                for (int g = 0; g < 4; ++g) {
                    bool ok = isdiag ? (n == wave) : (n * 16 + hi * 4 + g < vv);
                    float val = ok ? s4[n][g] * 0.125f : -3.0e38f;
                    p[n][g] = val;
                    mx = fmaxf(mx, val);
                }
            mx = fmaxf(mx, __shfl_xor(mx, 16, 64));
            mx = fmaxf(mx, __shfl_xor(mx, 32, 64));
            float m_new = fmaxf(m_run, mx);
            float scale = __expf(m_run - m_new);
            float psum = 0.f;
#pragma unroll
            for (int n = 0; n < 4; ++n)
#pragma unroll
                for (int g = 0; g < 4; ++g) {
                    float e = __expf(p[n][g] - m_new);
                    p[n][g] = e;
                    psum += e;
                }
            psum += __shfl_xor(psum, 16, 64);
            psum += __shfl_xor(psum, 32, 64);
            l_run = l_run * scale + psum;
            m_run = m_new;
#pragma unroll
            for (int dt = 0; dt < 4; ++dt) oacc[dt] *= scale;
#pragma unroll
            for (int n = 0; n < 4; ++n)
#pragma unroll
                for (int pr = 0; pr < 2; ++pr) {
                    uint32_t u = packbf2(p[n][pr * 2], p[n][pr * 2 + 1]);
                    *(uint32_t*)(psb + lo * 128 + ((n * 32 + hi * 8 + pr * 4) ^ swz)) = u;
                }
            bf16x8 pa0 = *(const bf16x8*)(psb + lo * 128 + ((hi * 16) ^ swz));
            bf16x8 pa1 = *(const bf16x8*)(psb + lo * 128 + ((64 + hi * 16) ^ swz));
#pragma unroll
            for (int dt = 0; dt < 4; ++dt) {
#pragma unroll
                for (int kk = 0; kk < 2; ++kk) {
                    const bf16x8 vf = *(const bf16x8*)((const char*)Vs[cur] +
                        ((dt * 16 + lo) << 7) + ((((kk << 2) + hi) ^ (lo & 7)) << 4));
                    oacc[dt] = MFMA16x32(vf, kk ? pa1 : pa0, oacc[dt]);
                }
            }
        }
        __builtin_amdgcn_s_barrier();
        __builtin_amdgcn_sched_barrier(0);
    }
#undef KB

    float inv = 1.f / l_run;
#pragma unroll
    for (int dt = 0; dt < 4; ++dt) {
        ushort4 st;
        st.x = f2bf(oacc[dt][0] * inv);
        st.y = f2bf(oacc[dt][1] * inv);
        st.z = f2bf(oacc[dt][2] * inv);
        st.w = f2bf(oacc[dt][3] * inv);
        *(ushort4*)&o[(row0 + lo) * DIM + head * 64 + dt * 16 + hi * 4] = st;
    }
}

extern "C" void kernel_launch(void* const* d_in, const int* in_sizes, int n_in,
                              void* d_out, int out_size, void* d_ws, size_t ws_size,
                              hipStream_t stream) {
    const float* x      = (const float*)d_in[0];
    const float* cosT   = (const float*)d_in[1];
    const float* sinT   = (const float*)d_in[2];
    const float* c      = (const float*)d_in[3];
    const float* W_qkv  = (const float*)d_in[4];
    const float* W_out  = (const float*)d_in[5];
    const float* ln1_w  = (const float*)d_in[6];
    const float* ln2_w  = (const float*)d_in[7];
    const float* mlp_w1 = (const float*)d_in[8];
    const float* mlp_b1 = (const float*)d_in[9];
    const float* mlp_w2 = (const float*)d_in[10];
    const float* mlp_b2 = (const float*)d_in[11];
    const float* ada_w  = (const float*)d_in[12];
    const float* ada_b  = (const float*)d_in[13];
    float* out = (float*)d_out;

    char* ws = (char*)d_ws;
    float*  ada   = (float*)(ws + 0);
    ushort* h     = (ushort*)(ws + 65536L);
    ushort* qkv   = (ushort*)(ws + 6356992L);       // also reused as split-K partials
    float*  part  = (float*)(ws + 6356992L);        // 2 x 4096 x 768 f32 = 25.2 MB
    ushort* vt    = (ushort*)(ws + 25231360L);
    ushort* o     = (ushort*)(ws + 31522816L);
    float*  x1    = (float*)(ws + 37814272L);
    ushort* a1    = (ushort*)(ws + 50397184L);
    ushort* wqkvT = (ushort*)(ws + 75563008L);
    ushort* woutT = (ushort*)(ws + 79101952L);
    ushort* w1T   = (ushort*)(ws + 80281600L);
    ushort* w2T   = (ushort*)(ws + 85000192L);

    ada_kernel<<<dim3(18, 2), 256, 0, stream>>>(c, ada_w, ada_b, ada);
    convT<<<dim3(36, 12), 256, 0, stream>>>(W_qkv, wqkvT, 768, 2304);
    convT<<<dim3(12, 12), 256, 0, stream>>>(W_out, woutT, 768, 768);
    convT<<<dim3(48, 12), 256, 0, stream>>>(mlp_w1, w1T, 768, 3072);
    convT<<<dim3(12, 48), 256, 0, stream>>>(mlp_w2, w2T, 3072, 768);

    ln_mod_kernel<<<TOKENS, 256, 0, stream>>>(x, ln1_w, ada, 0, 768, h);
    gemm_bf16<0, 128><<<dim3(18, 32), 256, 0, stream>>>(h, wqkvT, qkv, TOKENS, 2304, 768,
                                                        nullptr, nullptr, nullptr, cosT, sinT);
    vtrans<<<dim3(32, 12, 2), 256, 0, stream>>>(qkv, vt);
    attn_mfma<<<dim3(32, 12, 2), 256, 0, stream>>>(qkv, vt, o);
    gemm_bf16<1, 64><<<dim3(6, 64), 256, 0, stream>>>(o, woutT, x1, TOKENS, 768, 768,
                                                      nullptr, ada + 1536, x, nullptr, nullptr);
    ln_mod_kernel<<<TOKENS, 256, 0, stream>>>(x1, ln2_w, ada, 2304, 3072, h);
    gemm_bf16<2, 128><<<dim3(24, 32), 256, 0, stream>>>(h, w1T, a1, TOKENS, DFF, 768,
                                                        mlp_b1, nullptr, nullptr, nullptr, nullptr);
    // mlp2 as split-K=2 (partials into dead qkv region) + fused reduce/epilogue
    gemm_bf16<4, 64, 2><<<dim3(6, 64, 2), 256, 0, stream>>>(a1, w2T, part, TOKENS, 768, 1536,
                                                            nullptr, nullptr, nullptr, nullptr,
                                                            nullptr);
    splitk_red<<<3072, 256, 0, stream>>>(part, mlp_b2, ada, x1, out);
}